// Round 6
// baseline (1665.956 us; speedup 1.0000x reference)
//
#include <hip/hip_runtime.h>

#define Hh   256
#define NCn  20000
#define N1n  60000
#define N2n  60000
#define En   200000
#define Bn   512
#define OUTn 128
#define KA   96        // layer-0 packed-A stride / GEMM K
#define PGW  1792      // per-graph concat width (7 x 256)

using bf16x8 = __attribute__((ext_vector_type(8))) __bf16;
using f32x4  = __attribute__((ext_vector_type(4))) float;

__device__ __forceinline__ float bf2f(unsigned short u) {
    union { unsigned int i; float f; } v; v.i = ((unsigned int)u) << 16; return v.f;
}
__device__ __forceinline__ unsigned short f2bf(float f) {
    union { float f; unsigned int i; } v; v.f = f;
    unsigned int r = v.i + 0x7FFFu + ((v.i >> 16) & 1u);
    return (unsigned short)(r >> 16);
}
__device__ __forceinline__ int imax(int a, int b) { return a > b ? a : b; }

struct CPtr4 { const int* p[4]; };
struct IPtr4 { int* p[4]; };
struct IPtr8 { int* p[8]; };
struct UPtr4 { uint2* p[4]; };

// ---------------- input packing: raw features -> bf16 A-panels -------------------------
__global__ void pack_inputs(const float* __restrict__ xc, const float* __restrict__ x1,
                            const float* __restrict__ x2, unsigned short* __restrict__ A0,
                            unsigned short* __restrict__ A1, unsigned short* __restrict__ A2) {
    int idx = blockIdx.x * 256 + threadIdx.x;
    const int c0 = NCn * 64, c1 = c0 + N1n * 32, c2 = c1 + N2n * 32;
    if (idx < c0) {
        int m = idx >> 6, c = idx & 63;
        A0[(size_t)m * KA + c] = f2bf(xc[(size_t)m * 64 + c]);
    } else if (idx < c1) {
        int i = idx - c0; int m = i >> 5, c = i & 31;
        A1[(size_t)m * KA + 64 + c] = (c < 16) ? f2bf(x1[(size_t)m * 16 + c]) : (unsigned short)0;
    } else if (idx < c2) {
        int i = idx - c1; int m = i >> 5, c = i & 31;
        A2[(size_t)m * KA + 64 + c] = (c < 16) ? f2bf(x2[(size_t)m * 16 + c]) : (unsigned short)0;
    }
}

// ---------------- CSR build: BOTH dst-CSR (raw_agg) and src-CSR payload (pg_spmm) ------
// rel: 0 c2cont (src NC, dst N1), 1 cont2c (N1->NC), 2 c2categ (NC->N2), 3 categ2c (N2->NC)
// deg_all layout: [0,160000) dst-side degs, [160000,320000) src-side degs
__device__ __constant__ int off8_[8]  = { 0, 60000, 80000, 140000, 160000, 180000, 240000, 260000 };
__device__ __constant__ int n8_[8]    = { N1n, NCn, N2n, NCn, NCn, N1n, NCn, N2n };
__device__ __constant__ int cum8_[8]  = { 59, 79, 138, 158, 178, 237, 257, 316 };
__device__ __constant__ int nch8_[8]  = { 59, 20, 59, 20, 20, 59, 20, 59 };
__device__ __forceinline__ void rel_chunk8(int b, int& rel, int& c) {
    rel = 0;
    while (b >= cum8_[rel]) ++rel;
    c = b - (rel ? cum8_[rel - 1] : 0);
}

__global__ void zero_i32(int* p, int n) {
    int i = blockIdx.x * 256 + threadIdx.x; if (i < n) p[i] = 0;
}
__global__ void deg_count_all(CPtr4 src, CPtr4 dst, int* __restrict__ deg_all) {
    int i = blockIdx.x * 256 + threadIdx.x;
    if (i >= 8 * En) return;
    int rel = i / En; int e = i - rel * En;
    int node = (rel < 4) ? dst.p[rel][e] : src.p[rel - 4][e];
    atomicAdd(&deg_all[off8_[rel] + node], 1);
}
__global__ void __launch_bounds__(1024) scan_chunk_all(const int* __restrict__ deg_all,
                                                       IPtr8 rp, int* __restrict__ partials) {
    int rel, c; rel_chunk8(blockIdx.x, rel, c);
    int n = n8_[rel];
    __shared__ int sh[1024];
    int tid = threadIdx.x;
    int i = c * 1024 + tid;
    int v = (i < n) ? deg_all[off8_[rel] + i] : 0;
    sh[tid] = v; __syncthreads();
    for (int off = 1; off < 1024; off <<= 1) {
        int t = (tid >= off) ? sh[tid - off] : 0; __syncthreads();
        sh[tid] += t; __syncthreads();
    }
    if (i < n) rp.p[rel][i] = sh[tid] - v;
    if (tid == 1023) partials[rel * 64 + c] = sh[1023];
}
__global__ void scan_partials_all(int* partials) {   // grid 8 x 64 threads
    int rel = blockIdx.x;
    __shared__ int sh[64];
    int tid = threadIdx.x;
    int nch = nch8_[rel];
    int v = (tid < nch) ? partials[rel * 64 + tid] : 0;
    sh[tid] = v; __syncthreads();
    for (int off = 1; off < 64; off <<= 1) {
        int t = (tid >= off) ? sh[tid - off] : 0; __syncthreads();
        sh[tid] += t; __syncthreads();
    }
    if (tid < nch) partials[rel * 64 + tid] = sh[tid] - v;
}
__global__ void __launch_bounds__(1024) scan_add_all(IPtr8 rp, const int* __restrict__ partials) {
    int rel, c; rel_chunk8(blockIdx.x, rel, c);
    int n = n8_[rel];
    int tid = threadIdx.x;
    int i = c * 1024 + tid;
    if (i < n) rp.p[rel][i] += partials[rel * 64 + c];
    if (c == 0 && tid == 0) rp.p[rel][n] = En;
}
// dual scatter: dst-CSR colsrc (for raw_agg) + src-CSR payload {graph(dst), 1/deg(dst)}
__global__ void scatter_all(CPtr4 src, CPtr4 dst, CPtr4 rp, CPtr4 rq, CPtr4 batchdst,
                            int* fillD, int* fillS, IPtr4 cs, UPtr4 pay) {
    const int offD[4] = { 0, 60000, 80000, 140000 };
    const int offS[4] = { 0, 20000, 80000, 100000 };
    int i = blockIdx.x * 256 + threadIdx.x;
    if (i >= 4 * En) return;
    int rel = i / En; int e = i - rel * En;
    int v = src.p[rel][e], d = dst.p[rel][e];
    int rb = rp.p[rel][d];
    int posD = rb + atomicAdd(&fillD[offD[rel] + d], 1);
    cs.p[rel][posD] = v;
    int deg = rp.p[rel][d + 1] - rb;
    float w = 1.0f / (float)deg;
    unsigned int g = (unsigned int)batchdst.p[rel][d];
    int posS = rq.p[rel][v] + atomicAdd(&fillS[offS[rel] + v], 1);
    pay.p[rel][posS] = make_uint2(g, __float_as_uint(w));
}

// ---------------- raw-feature segment mean (layer 0), 2-way edge ILP -------------------
struct RawDesc {
    const unsigned short* feat;   // stride 96
    const int* rowptr;
    const int* colsrc;
    unsigned short* out;          // stride 96
    int sh;                       // log2(col-groups of 4)
    int n_dst;
    int ocol;
};
__global__ void raw_agg(RawDesc d0, RawDesc d1, RawDesc d2, RawDesc d3) {
    RawDesc d = (blockIdx.y == 0) ? d0 : (blockIdx.y == 1) ? d1 : (blockIdx.y == 2) ? d2 : d3;
    int idx = blockIdx.x * 256 + threadIdx.x;
    int node = idx >> d.sh;
    int c4 = idx & ((1 << d.sh) - 1);
    if (node >= d.n_dst) return;
    int s = d.rowptr[node], e = d.rowptr[node + 1];
    float a0 = 0.f, a1 = 0.f, a2 = 0.f, a3 = 0.f;
    float b0 = 0.f, b1 = 0.f, b2 = 0.f, b3 = 0.f;
    int i = s;
    for (; i + 1 < e; i += 2) {
        int sc1 = d.colsrc[i], sc2 = d.colsrc[i + 1];
        ushort4 v1 = *reinterpret_cast<const ushort4*>(d.feat + (size_t)sc1 * KA + c4 * 4);
        ushort4 v2 = *reinterpret_cast<const ushort4*>(d.feat + (size_t)sc2 * KA + c4 * 4);
        a0 += bf2f(v1.x); a1 += bf2f(v1.y); a2 += bf2f(v1.z); a3 += bf2f(v1.w);
        b0 += bf2f(v2.x); b1 += bf2f(v2.y); b2 += bf2f(v2.z); b3 += bf2f(v2.w);
    }
    if (i < e) {
        int sc1 = d.colsrc[i];
        ushort4 v1 = *reinterpret_cast<const ushort4*>(d.feat + (size_t)sc1 * KA + c4 * 4);
        a0 += bf2f(v1.x); a1 += bf2f(v1.y); a2 += bf2f(v1.z); a3 += bf2f(v1.w);
    }
    a0 += b0; a1 += b1; a2 += b2; a3 += b3;
    float inv = 1.0f / (float)imax(e - s, 1);
    ushort4 o;
    o.x = f2bf(a0 * inv); o.y = f2bf(a1 * inv); o.z = f2bf(a2 * inv); o.w = f2bf(a3 * inv);
    *reinterpret_cast<ushort4*>(d.out + (size_t)node * KA + d.ocol + c4 * 4) = o;
}

// ---------------- layer-0 weight folding ------------------------------------------------
__global__ void wfold(const float* __restrict__ Wm, const float* __restrict__ Wr,
                      const float* __restrict__ Wpc, const float* __restrict__ Wp1,
                      const float* __restrict__ Wp2, unsigned short* __restrict__ Wt3) {
    __shared__ float cA[256], cB[256], cC[256];
    int n = blockIdx.x, mat = blockIdx.y, tid = threadIdx.x;
    for (int j = tid; j < 256; j += 128) {
        if (mat == 0) {
            cA[j] = 0.5f * (Wr[1 * 65536 + j * 256 + n] + Wr[3 * 65536 + j * 256 + n]);
            cB[j] = 0.5f * Wm[1 * 65536 + j * 256 + n];
            cC[j] = 0.5f * Wm[3 * 65536 + j * 256 + n];
        } else if (mat == 1) {
            cA[j] = Wm[0 * 65536 + j * 256 + n];
            cB[j] = Wr[0 * 65536 + j * 256 + n];
            cC[j] = 0.f;
        } else {
            cA[j] = Wm[2 * 65536 + j * 256 + n];
            cB[j] = Wr[2 * 65536 + j * 256 + n];
            cC[j] = 0.f;
        }
    }
    __syncthreads();
    int k = tid;
    if (k >= KA) return;
    float w = 0.f;
    if (k < 64) {
        for (int j = 0; j < 256; ++j) w = fmaf(Wpc[k * 256 + j], cA[j], w);
    } else if (k < 80) {
        const float* Wp = (mat == 2) ? Wp2 : Wp1;
        for (int j = 0; j < 256; ++j) w = fmaf(Wp[(k - 64) * 256 + j], cB[j], w);
    } else if (mat == 0) {
        for (int j = 0; j < 256; ++j) w = fmaf(Wp2[(k - 80) * 256 + j], cC[j], w);
    }
    Wt3[(size_t)mat * 256 * KA + n * KA + k] = f2bf(w);
}

__global__ void bias_fold(const float* __restrict__ Wm, const float* __restrict__ Wr,
                          const float* __restrict__ bm, const float* __restrict__ bpc,
                          const float* __restrict__ bp1, const float* __restrict__ bp2,
                          float* __restrict__ bC, float* __restrict__ bB1, float* __restrict__ bB2) {
    int n = blockIdx.x * 128 + threadIdx.x;
    if (n >= 256) return;
    float s0 = 0, s1 = 0, s2 = 0, t0 = 0, t1 = 0, u0 = 0, u1 = 0;
    for (int j = 0; j < 256; ++j) {
        float wr1 = Wr[1 * 65536 + j * 256 + n], wr3 = Wr[3 * 65536 + j * 256 + n];
        float wm1 = Wm[1 * 65536 + j * 256 + n], wm3 = Wm[3 * 65536 + j * 256 + n];
        float wm0 = Wm[0 * 65536 + j * 256 + n], wr0 = Wr[0 * 65536 + j * 256 + n];
        float wm2 = Wm[2 * 65536 + j * 256 + n], wr2 = Wr[2 * 65536 + j * 256 + n];
        float bc = bpc[j], b1 = bp1[j], b2 = bp2[j];
        s0 = fmaf(bc, 0.5f * (wr1 + wr3), s0);
        s1 = fmaf(b1, 0.5f * wm1, s1);
        s2 = fmaf(b2, 0.5f * wm3, s2);
        t0 = fmaf(bc, wm0, t0); t1 = fmaf(b1, wr0, t1);
        u0 = fmaf(bc, wm2, u0); u1 = fmaf(b2, wr2, u1);
    }
    bC[n]  = s0 + s1 + s2 + 0.5f * (bm[1 * 256 + n] + bm[3 * 256 + n]);
    bB1[n] = t0 + t1 + bm[0 * 256 + n];
    bB2[n] = u0 + u1 + bm[2 * 256 + n];
}

// layer-1 stacked per-graph weight [256][1792] transposed bf16 (x 1/3), + bias
__global__ void wpg_prep(const float* __restrict__ Wm, const float* __restrict__ Wr,
                         const float* __restrict__ bm, unsigned short* __restrict__ WPGt,
                         float* __restrict__ bPG) {
    int idx = blockIdx.x * 256 + threadIdx.x;
    const float third = 1.0f / 3.0f;
    if (idx < 256 * PGW) {
        int n = idx / PGW, k = idx - n * PGW;
        int blk = k >> 8, kk = k & 255;
        float v;
        switch (blk) {
            case 0:  v = 0.5f * Wm[1 * 65536 + kk * 256 + n]; break;
            case 1:  v = 0.5f * Wm[3 * 65536 + kk * 256 + n]; break;
            case 2:  v = 0.5f * (Wr[1 * 65536 + kk * 256 + n] + Wr[3 * 65536 + kk * 256 + n]); break;
            case 3:  v = Wm[0 * 65536 + kk * 256 + n]; break;
            case 4:  v = Wr[0 * 65536 + kk * 256 + n]; break;
            case 5:  v = Wm[2 * 65536 + kk * 256 + n]; break;
            default: v = Wr[2 * 65536 + kk * 256 + n]; break;
        }
        WPGt[idx] = f2bf(v * third);
    } else if (idx < 256 * PGW + 256) {
        int n = idx - 256 * PGW;
        bPG[n] = third * (0.5f * (bm[1 * 256 + n] + bm[3 * 256 + n]) + bm[0 * 256 + n] + bm[2 * 256 + n]);
    }
}

// ---------------- layer-0 GEMM: K=96, N=256, bias+relu, 3 fused instances --------------
struct G96 {
    const unsigned short* A;
    const unsigned short* Wt;
    const float* bias;
    unsigned short* C;
    int M;
};
__global__ void __launch_bounds__(256) gemm96(G96 g0, G96 g1, G96 g2) {
    G96 g = (blockIdx.y == 0) ? g0 : (blockIdx.y == 1) ? g1 : g2;
    const int m0 = blockIdx.x * 32;
    if (m0 >= g.M) return;
    const int tid = threadIdx.x;
    const int wid = tid >> 6, lane = tid & 63;
    const int llo = lane & 15, lhi = lane >> 4;
    const int cb = wid * 64;

    const unsigned short* pA[2];
#pragma unroll
    for (int rt = 0; rt < 2; ++rt)
        pA[rt] = g.A + (size_t)(m0 + rt * 16 + llo) * KA + lhi * 8;
    const unsigned short* pB[4];
#pragma unroll
    for (int ct = 0; ct < 4; ++ct)
        pB[ct] = g.Wt + (size_t)(cb + ct * 16 + llo) * KA + lhi * 8;

    f32x4 acc[2][4] = {};
    bf16x8 a0[2], a1[2], a2[2], b0[4], b1[4], b2[4];
#pragma unroll
    for (int t = 0; t < 2; ++t) {
        a0[t] = *reinterpret_cast<const bf16x8*>(pA[t]);
        a1[t] = *reinterpret_cast<const bf16x8*>(pA[t] + 32);
        a2[t] = *reinterpret_cast<const bf16x8*>(pA[t] + 64);
    }
#pragma unroll
    for (int t = 0; t < 4; ++t) {
        b0[t] = *reinterpret_cast<const bf16x8*>(pB[t]);
        b1[t] = *reinterpret_cast<const bf16x8*>(pB[t] + 32);
        b2[t] = *reinterpret_cast<const bf16x8*>(pB[t] + 64);
    }
#pragma unroll
    for (int rt = 0; rt < 2; ++rt)
#pragma unroll
        for (int ct = 0; ct < 4; ++ct) {
            acc[rt][ct] = __builtin_amdgcn_mfma_f32_16x16x32_bf16(b0[ct], a0[rt], acc[rt][ct], 0, 0, 0);
            acc[rt][ct] = __builtin_amdgcn_mfma_f32_16x16x32_bf16(b1[ct], a1[rt], acc[rt][ct], 0, 0, 0);
            acc[rt][ct] = __builtin_amdgcn_mfma_f32_16x16x32_bf16(b2[ct], a2[rt], acc[rt][ct], 0, 0, 0);
        }

#pragma unroll
    for (int rt = 0; rt < 2; ++rt) {
        const int row = m0 + rt * 16 + llo;
#pragma unroll
        for (int ct = 0; ct < 4; ++ct) {
            const int col0 = cb + ct * 16 + lhi * 4;
            float4 bv = *reinterpret_cast<const float4*>(g.bias + col0);
            float v0 = fmaxf(acc[rt][ct][0] + bv.x, 0.f);
            float v1 = fmaxf(acc[rt][ct][1] + bv.y, 0.f);
            float v2 = fmaxf(acc[rt][ct][2] + bv.z, 0.f);
            float v3 = fmaxf(acc[rt][ct][3] + bv.w, 0.f);
            ushort4 o;
            o.x = f2bf(v0); o.y = f2bf(v1); o.z = f2bf(v2); o.w = f2bf(v3);
            *reinterpret_cast<ushort4*>(g.C + (size_t)row * Hh + col0) = o;
        }
    }
}

// ---------------- per-graph edge aggregation: src-major SpMM into LDS ------------------
// PGacc[g][col] += (1/deg_dst) * feat[src][col], streamed over src rows (sequential).
// grid (chunk=8, colblock=8, desc=4); 64 KB LDS acc[512 graphs][32 cols].
struct SpmmDesc {
    const unsigned short* feat;   // [n_src][256]
    const int* rowptr;            // src-CSR, n_src+1
    const uint2* pay;             // per edge (src-order): {graph(dst), 1/deg_dst}
    int n_src, chunk_sz;
};
__global__ void __launch_bounds__(256) pg_spmm(SpmmDesc d0, SpmmDesc d1, SpmmDesc d2, SpmmDesc d3,
                                               float* __restrict__ partial) {
    __shared__ float acc[512 * 32];
    SpmmDesc d = (blockIdx.z == 0) ? d0 : (blockIdx.z == 1) ? d1 : (blockIdx.z == 2) ? d2 : d3;
    const int cb = blockIdx.y;
    const int chunk = blockIdx.x;
    const int tid = threadIdx.x;
    f32x4* accv = reinterpret_cast<f32x4*>(acc);
    for (int i = tid; i < 512 * 32 / 4; i += 256) accv[i] = f32x4{0.f, 0.f, 0.f, 0.f};
    __syncthreads();
    const int wid = tid >> 6, lane = tid & 63;
    const int col = lane & 31, half = lane >> 5;
    int v0 = chunk * d.chunk_sz;
    int v1 = v0 + d.chunk_sz; if (v1 > d.n_src) v1 = d.n_src;
    for (int v = v0 + wid; v < v1; v += 4) {
        int es = d.rowptr[v], ee = d.rowptr[v + 1];
        if (es >= ee) continue;
        float f = bf2f(d.feat[(size_t)v * Hh + cb * 32 + col]);
        for (int e = es; e < ee; e += 2) {
            int ei = e + half;
            if (ei < ee) {
                uint2 p = d.pay[ei];
                atomicAdd(&acc[p.x * 32 + col], f * __uint_as_float(p.y));
            }
        }
    }
    __syncthreads();
    float* dst = partial + (size_t)((blockIdx.z * 8 + cb) * 8 + chunk) * (512 * 32);
    f32x4* dv = reinterpret_cast<f32x4*>(dst);
    for (int i = tid; i < 512 * 32 / 4; i += 256) dv[i] = accv[i];
}

// reduce partials over 8 chunks, normalize by per-graph node count, write bf16 PG slots
__global__ void __launch_bounds__(256) pg_reduce(const float* __restrict__ partial,
                                                 const int* __restrict__ bounds,
                                                 unsigned short* __restrict__ PG) {
    int g = blockIdx.x;          // 512
    int z = blockIdx.y;          // 4 descriptors
    int col = threadIdx.x;       // 256
    int cb = col >> 5, c = col & 31;
    const float* p = partial + (size_t)(z * 8 + cb) * 8 * (512 * 32) + g * 32 + c;
    float s = 0.f;
#pragma unroll
    for (int ch = 0; ch < 8; ++ch) s += p[(size_t)ch * 512 * 32];
    const int ntab[4] = { 0, 0, 1, 2 };
    const int otab[4] = { 0, 256, 768, 1280 };
    const int* b = bounds + ntab[z] * (Bn + 1);
    int cnt = b[g + 1] - b[g];
    s *= 1.0f / (float)imax(cnt, 1);
    PG[(size_t)g * PGW + otab[z] + col] = f2bf(s);
}

// ---------------- plain per-graph node means (sequential rows) -------------------------
struct PlainDesc { const unsigned short* feat; const int* bound; int ocol; };
__global__ void __launch_bounds__(256) pg_plain(PlainDesc d0, PlainDesc d1, PlainDesc d2,
                                                unsigned short* __restrict__ PG) {
    PlainDesc d = (blockIdx.y == 0) ? d0 : (blockIdx.y == 1) ? d1 : d2;
    int g = blockIdx.x;
    int ns = d.bound[g], ne = d.bound[g + 1];
    int tid = threadIdx.x, wid = tid >> 6, lane = tid & 63;
    float a0 = 0.f, a1 = 0.f, a2 = 0.f, a3 = 0.f;
    float c0 = 0.f, c1 = 0.f, c2 = 0.f, c3 = 0.f;
    for (int n = ns + wid; n < ne; n += 8) {
        ushort4 v1 = *reinterpret_cast<const ushort4*>(d.feat + (size_t)n * Hh + lane * 4);
        int n2 = n + 4;
        if (n2 < ne) {
            ushort4 v2 = *reinterpret_cast<const ushort4*>(d.feat + (size_t)n2 * Hh + lane * 4);
            c0 += bf2f(v2.x); c1 += bf2f(v2.y); c2 += bf2f(v2.z); c3 += bf2f(v2.w);
        }
        a0 += bf2f(v1.x); a1 += bf2f(v1.y); a2 += bf2f(v1.z); a3 += bf2f(v1.w);
    }
    a0 += c0; a1 += c1; a2 += c2; a3 += c3;
    __shared__ float sh[4][256];
    sh[wid][lane * 4 + 0] = a0; sh[wid][lane * 4 + 1] = a1;
    sh[wid][lane * 4 + 2] = a2; sh[wid][lane * 4 + 3] = a3;
    __syncthreads();
    float r = sh[0][tid] + sh[1][tid] + sh[2][tid] + sh[3][tid];
    r *= 1.0f / (float)imax(ne - ns, 1);
    PG[(size_t)g * PGW + d.ocol + tid] = f2bf(r);
}

// ---------------- final: emb = PG @ WPGt + bPG (MFMA); out = emb @ Wg + bg -------------
__global__ void graph_bounds_all(const int* __restrict__ bc, const int* __restrict__ b1,
                                 const int* __restrict__ b2, int* __restrict__ bound) {
    int idx = blockIdx.x * 256 + threadIdx.x;
    if (idx >= 3 * (Bn + 1)) return;
    int t = idx / (Bn + 1); int b = idx - t * (Bn + 1);
    const int* batch = (t == 0) ? bc : (t == 1) ? b1 : b2;
    int n = (t == 0) ? NCn : (t == 1) ? N1n : N2n;
    int lo = 0, hi = n;
    while (lo < hi) { int mid = (lo + hi) >> 1; if (batch[mid] < b) lo = mid + 1; else hi = mid; }
    bound[idx] = lo;
}

__global__ void __launch_bounds__(256) gemm_emb(const unsigned short* __restrict__ PG,
                                                const unsigned short* __restrict__ WPGt,
                                                const float* __restrict__ bPG,
                                                float* __restrict__ emb) {
    constexpr int KSTEPS = PGW / 32;
    const int m0 = blockIdx.x * 32;
    const int tid = threadIdx.x;
    const int wid = tid >> 6, lane = tid & 63;
    const int llo = lane & 15, lhi = lane >> 4;
    const int cb = wid * 64;

    const unsigned short* pA[2];
#pragma unroll
    for (int rt = 0; rt < 2; ++rt)
        pA[rt] = PG + (size_t)(m0 + rt * 16 + llo) * PGW + lhi * 8;
    const unsigned short* pB[4];
#pragma unroll
    for (int ct = 0; ct < 4; ++ct)
        pB[ct] = WPGt + (size_t)(cb + ct * 16 + llo) * PGW + lhi * 8;

    f32x4 acc[2][4] = {};
    bf16x8 aX[2], bX[4], aY[2], bY[4];
    auto LD = [&](bf16x8 (&a)[2], bf16x8 (&b)[4], int ks) {
        if (ks < KSTEPS) {
            const int ko = ks * 32;
#pragma unroll
            for (int t = 0; t < 2; ++t) a[t] = *reinterpret_cast<const bf16x8*>(pA[t] + ko);
#pragma unroll
            for (int t = 0; t < 4; ++t) b[t] = *reinterpret_cast<const bf16x8*>(pB[t] + ko);
        }
    };
    auto FM = [&](bf16x8 (&a)[2], bf16x8 (&b)[4]) {
#pragma unroll
        for (int rt = 0; rt < 2; ++rt)
#pragma unroll
            for (int ct = 0; ct < 4; ++ct)
                acc[rt][ct] = __builtin_amdgcn_mfma_f32_16x16x32_bf16(b[ct], a[rt], acc[rt][ct], 0, 0, 0);
    };
    LD(aX, bX, 0);
    for (int ks = 0; ks < KSTEPS; ks += 2) {
        LD(aY, bY, ks + 1);
        FM(aX, bX);
        LD(aX, bX, ks + 2);
        FM(aY, bY);
    }

#pragma unroll
    for (int rt = 0; rt < 2; ++rt) {
        const int row = m0 + rt * 16 + llo;
#pragma unroll
        for (int ct = 0; ct < 4; ++ct) {
            const int col0 = cb + ct * 16 + lhi * 4;
            float4 bv = *reinterpret_cast<const float4*>(bPG + col0);
            float4 o;
            o.x = acc[rt][ct][0] + bv.x; o.y = acc[rt][ct][1] + bv.y;
            o.z = acc[rt][ct][2] + bv.z; o.w = acc[rt][ct][3] + bv.w;
            *reinterpret_cast<float4*>(emb + (size_t)row * Hh + col0) = o;
        }
    }
}

__global__ void __launch_bounds__(128) out_final(const float* __restrict__ emb,
                                                 const float* __restrict__ Wg,
                                                 const float* __restrict__ bg,
                                                 float* __restrict__ out) {
    __shared__ float es_[256];
    int g = blockIdx.x, o = threadIdx.x;
    es_[o] = emb[(size_t)g * Hh + o];
    es_[o + 128] = emb[(size_t)g * Hh + 128 + o];
    __syncthreads();
    float acc = bg[o];
#pragma unroll 8
    for (int k = 0; k < 256; ++k) acc = fmaf(es_[k], Wg[k * OUTn + o], acc);
    out[(size_t)g * OUTn + o] = acc;
}

// ---------------- host orchestration ----------------------------------------------------
extern "C" void kernel_launch(void* const* d_in, const int* in_sizes, int n_in,
                              void* d_out, int out_size, void* d_ws, size_t ws_size,
                              hipStream_t stream) {
    const float* x_central = (const float*)d_in[0];
    const float* x_cont    = (const float*)d_in[1];
    const float* x_categ   = (const float*)d_in[2];
    const int* ei_c2cont   = (const int*)d_in[3];
    const int* ei_cont2c   = (const int*)d_in[4];
    const int* ei_c2categ  = (const int*)d_in[5];
    const int* ei_categ2c  = (const int*)d_in[6];
    const int* batch_central = (const int*)d_in[7];
    const int* batch_cont    = (const int*)d_in[8];
    const int* batch_categ   = (const int*)d_in[9];
    const float* Wp_central = (const float*)d_in[11];
    const float* bp_central = (const float*)d_in[12];
    const float* Wp_cont    = (const float*)d_in[13];
    const float* bp_cont    = (const float*)d_in[14];
    const float* Wp_categ   = (const float*)d_in[15];
    const float* bp_categ   = (const float*)d_in[16];
    const float* W_msg  = (const float*)d_in[17];
    const float* b_msg  = (const float*)d_in[18];
    const float* W_root = (const float*)d_in[19];
    const float* Wg     = (const float*)d_in[20];
    const float* bg     = (const float*)d_in[21];
    float* out = (float*)d_out;

    char* base = (char*)d_ws;
    size_t off = 0;
    auto alloc = [&](size_t bytes) -> void* {
        off = (off + 255) & ~(size_t)255;
        void* p = base + off; off += bytes; return p;
    };

    unsigned short* A0  = (unsigned short*)alloc((size_t)NCn * KA * 2);
    unsigned short* A1  = (unsigned short*)alloc((size_t)N1n * KA * 2);
    unsigned short* A2  = (unsigned short*)alloc((size_t)N2n * KA * 2);
    unsigned short* hc1 = (unsigned short*)alloc((size_t)NCn * Hh * 2);
    unsigned short* h11 = (unsigned short*)alloc((size_t)N1n * Hh * 2);
    unsigned short* h21 = (unsigned short*)alloc((size_t)N2n * Hh * 2);
    unsigned short* PG  = (unsigned short*)alloc((size_t)Bn * PGW * 2);
    float* emb          = (float*)alloc((size_t)Bn * Hh * 4);

    unsigned short* Wt3  = (unsigned short*)alloc((size_t)3 * 256 * KA * 2);
    unsigned short* WPGt = (unsigned short*)alloc((size_t)256 * PGW * 2);
    float* bC  = (float*)alloc(256 * 4);
    float* bB1 = (float*)alloc(256 * 4);
    float* bB2 = (float*)alloc(256 * 4);
    float* bPG = (float*)alloc(256 * 4);

    const int ndst[4] = { N1n, NCn, N2n, NCn };
    const int nsrc[4] = { NCn, N1n, NCn, N2n };
    int* rp[4]; int* cs[4]; int* rq[4]; uint2* pay[4];
    for (int r = 0; r < 4; ++r) {
        rp[r]  = (int*)alloc((size_t)(ndst[r] + 1) * 4);
        cs[r]  = (int*)alloc((size_t)En * 4);
        rq[r]  = (int*)alloc((size_t)(nsrc[r] + 1) * 4);
        pay[r] = (uint2*)alloc((size_t)En * 8);
    }
    int* deg_fill = (int*)alloc((size_t)640000 * 4);   // [0,320000) deg, [320000,640000) fill
    int* partials = (int*)alloc(512 * 4);
    int* bounds   = (int*)alloc((size_t)3 * (Bn + 1) * 4);
    // partial SpMM buffer (16.78 MB) aliases the A-panels, which are dead after gemm96
    float* partial = (float*)A0;
    (void)ws_size; (void)in_sizes; (void)n_in; (void)out_size;

    const float* Wm0 = W_msg;
    const float* Wr0 = W_root;
    const float* Wm1 = W_msg  + (size_t)4 * 65536;
    const float* Wr1 = W_root + (size_t)4 * 65536;
    const float* bm0 = b_msg;
    const float* bm1 = b_msg + 4 * 256;

    // --- packing + weight prep ---
    pack_inputs<<<20000, 256, 0, stream>>>(x_central, x_cont, x_categ, A0, A1, A2);
    wfold<<<dim3(256, 3), 128, 0, stream>>>(Wm0, Wr0, Wp_central, Wp_cont, Wp_categ, Wt3);
    bias_fold<<<2, 128, 0, stream>>>(Wm0, Wr0, bm0, bp_central, bp_cont, bp_categ, bC, bB1, bB2);
    wpg_prep<<<1793, 256, 0, stream>>>(Wm1, Wr1, bm1, WPGt, bPG);
    graph_bounds_all<<<7, 256, 0, stream>>>(batch_central, batch_cont, batch_categ, bounds);

    // --- CSR build (both sides) ---
    CPtr4 srcs = {{ ei_c2cont, ei_cont2c, ei_c2categ, ei_categ2c }};
    CPtr4 dsts = {{ ei_c2cont + En, ei_cont2c + En, ei_c2categ + En, ei_categ2c + En }};
    IPtr8 rpq  = {{ rp[0], rp[1], rp[2], rp[3], rq[0], rq[1], rq[2], rq[3] }};
    CPtr4 rpc  = {{ rp[0], rp[1], rp[2], rp[3] }};
    CPtr4 rqc  = {{ rq[0], rq[1], rq[2], rq[3] }};
    IPtr4 css  = {{ cs[0], cs[1], cs[2], cs[3] }};
    UPtr4 pys  = {{ pay[0], pay[1], pay[2], pay[3] }};
    CPtr4 bds  = {{ batch_cont, batch_central, batch_categ, batch_central }};
    zero_i32<<<2500, 256, 0, stream>>>(deg_fill, 640000);
    deg_count_all<<<6250, 256, 0, stream>>>(srcs, dsts, deg_fill);
    scan_chunk_all<<<316, 1024, 0, stream>>>(deg_fill, rpq, partials);
    scan_partials_all<<<8, 64, 0, stream>>>(partials);
    scan_add_all<<<316, 1024, 0, stream>>>(rpq, partials);
    scatter_all<<<3125, 256, 0, stream>>>(srcs, dsts, rpc, rqc, bds,
                                          deg_fill + 320000, deg_fill + 480000, css, pys);

    // --- layer-0 raw aggregations (into A panels) ---
    RawDesc r0 = { A1 + 64, rp[1], cs[1], A0, 2, NCn, 64 };
    RawDesc r1 = { A2 + 64, rp[3], cs[3], A0, 2, NCn, 80 };
    RawDesc r2 = { A0,      rp[0], cs[0], A1, 4, N1n, 0 };
    RawDesc r3 = { A0,      rp[2], cs[2], A2, 4, N2n, 0 };
    raw_agg<<<dim3(3750, 4), 256, 0, stream>>>(r0, r1, r2, r3);

    // --- layer-0 GEMMs (K=96, bias+relu) ---
    G96 gc = { A0, Wt3,                 bC,  hc1, NCn };
    G96 g1 = { A1, Wt3 + 1 * 256 * KA,  bB1, h11, N1n };
    G96 g2 = { A2, Wt3 + 2 * 256 * KA,  bB2, h21, N2n };
    gemm96<<<dim3(1875, 3), 256, 0, stream>>>(g1, g2, gc);

    // --- layer-1 collapsed: src-major SpMM + plain means (A panels now dead -> partial) ---
    SpmmDesc s0 = { h11, rq[1], pay[1], N1n, (N1n + 7) / 8 };   // cont2c  -> ocol 0
    SpmmDesc s1 = { h21, rq[3], pay[3], N2n, (N2n + 7) / 8 };   // categ2c -> ocol 256
    SpmmDesc s2 = { hc1, rq[0], pay[0], NCn, (NCn + 7) / 8 };   // c2cont  -> ocol 768
    SpmmDesc s3 = { hc1, rq[2], pay[2], NCn, (NCn + 7) / 8 };   // c2categ -> ocol 1280
    pg_spmm<<<dim3(8, 8, 4), 256, 0, stream>>>(s0, s1, s2, s3, partial);
    PlainDesc p0 = { hc1, bounds,                512 };
    PlainDesc p1 = { h11, bounds + (Bn + 1),     1024 };
    PlainDesc p2 = { h21, bounds + 2 * (Bn + 1), 1536 };
    pg_plain<<<dim3(Bn, 3), 256, 0, stream>>>(p0, p1, p2, PG);
    pg_reduce<<<dim3(Bn, 4), 256, 0, stream>>>(partial, bounds, PG);

    // --- final ---
    gemm_emb<<<Bn / 32, 256, 0, stream>>>(PG, WPGt, bPG, emb);
    out_final<<<Bn, 128, 0, stream>>>(emb, Wg, bg, out);
}

// Round 7
// 351.811 us; speedup vs baseline: 4.7354x; 4.7354x over previous
//
#include <hip/hip_runtime.h>

#define Hh   256
#define NCn  20000
#define N1n  60000
#define N2n  60000
#define En   200000
#define Bn   512
#define OUTn 128
#define KA   96        // layer-0 packed-A stride / GEMM K
#define PGW  1792      // per-graph concat width (7 x 256)

using bf16x8 = __attribute__((ext_vector_type(8))) __bf16;
using f32x4  = __attribute__((ext_vector_type(4))) float;

__device__ __forceinline__ float bf2f(unsigned short u) {
    union { unsigned int i; float f; } v; v.i = ((unsigned int)u) << 16; return v.f;
}
__device__ __forceinline__ unsigned short f2bf(float f) {
    union { float f; unsigned int i; } v; v.f = f;
    unsigned int r = v.i + 0x7FFFu + ((v.i >> 16) & 1u);
    return (unsigned short)(r >> 16);
}
__device__ __forceinline__ int imax(int a, int b) { return a > b ? a : b; }

struct CPtr4 { const int* p[4]; };
struct IPtr4 { int* p[4]; };
struct FPtr4 { float* p[4]; };

// ---------------- input packing: raw features -> bf16 A-panels (float4 vectorized) -----
__global__ void pack_inputs(const float* __restrict__ xc, const float* __restrict__ x1,
                            const float* __restrict__ x2, unsigned short* __restrict__ A0,
                            unsigned short* __restrict__ A1, unsigned short* __restrict__ A2) {
    int idx = blockIdx.x * 256 + threadIdx.x;   // one ushort4 (4 cols) per thread
    const int c0 = NCn * 16, c1 = c0 + N1n * 8, c2 = c1 + N2n * 8;
    if (idx < c0) {
        int m = idx >> 4, c = (idx & 15) * 4;
        float4 v = *reinterpret_cast<const float4*>(xc + (size_t)m * 64 + c);
        ushort4 o = { f2bf(v.x), f2bf(v.y), f2bf(v.z), f2bf(v.w) };
        *reinterpret_cast<ushort4*>(A0 + (size_t)m * KA + c) = o;
    } else if (idx < c2) {
        bool is1 = idx < c1;
        int i = idx - (is1 ? c0 : c1);
        int m = i >> 3, c = (i & 7) * 4;
        const float* x = is1 ? x1 : x2;
        unsigned short* A = is1 ? A1 : A2;
        ushort4 o = { 0, 0, 0, 0 };
        if (c < 16) {
            float4 v = *reinterpret_cast<const float4*>(x + (size_t)m * 16 + c);
            o.x = f2bf(v.x); o.y = f2bf(v.y); o.z = f2bf(v.z); o.w = f2bf(v.w);
        }
        *reinterpret_cast<ushort4*>(A + (size_t)m * KA + 64 + c) = o;
    }
}

// ---------------- CSR build (relation-batched, dst side only) --------------------------
// rel: 0 c2cont (dst N1), 1 cont2c (dst NC), 2 c2categ (dst N2), 3 categ2c (dst NC)
__device__ __forceinline__ int degoff_of(int rel) {
    const int t[4] = { 0, N1n, N1n + NCn, N1n + NCn + N2n };
    return t[rel];
}
__device__ __forceinline__ int nrel_of(int rel) {
    const int t[4] = { N1n, NCn, N2n, NCn };
    return t[rel];
}
__device__ __forceinline__ void rel_chunk(int b, int& rel, int& c) {
    if (b < 59)       { rel = 0; c = b; }
    else if (b < 79)  { rel = 1; c = b - 59; }
    else if (b < 138) { rel = 2; c = b - 79; }
    else              { rel = 3; c = b - 138; }
}
__global__ void zero_i32(int* p, int n) {
    int i = blockIdx.x * 256 + threadIdx.x; if (i < n) p[i] = 0;
}
__global__ void deg_count_all(CPtr4 dst, int* __restrict__ deg_all) {
    int i = blockIdx.x * 256 + threadIdx.x;
    if (i >= 4 * En) return;
    int rel = i / En; int e = i - rel * En;
    atomicAdd(&deg_all[degoff_of(rel) + dst.p[rel][e]], 1);
}
__global__ void __launch_bounds__(1024) scan_chunk_all(const int* __restrict__ deg_all,
                                                       IPtr4 rp, int* __restrict__ partials) {
    int rel, c; rel_chunk(blockIdx.x, rel, c);
    int n = nrel_of(rel);
    __shared__ int sh[1024];
    int tid = threadIdx.x;
    int i = c * 1024 + tid;
    int v = (i < n) ? deg_all[degoff_of(rel) + i] : 0;
    sh[tid] = v; __syncthreads();
    for (int off = 1; off < 1024; off <<= 1) {
        int t = (tid >= off) ? sh[tid - off] : 0; __syncthreads();
        sh[tid] += t; __syncthreads();
    }
    if (i < n) rp.p[rel][i] = sh[tid] - v;
    if (tid == 1023) partials[rel * 64 + c] = sh[1023];
}
__global__ void scan_partials_all(int* partials) {
    const int nch[4] = { 59, 20, 59, 20 };
    int rel = blockIdx.x;
    __shared__ int sh[64];
    int tid = threadIdx.x;
    int v = (tid < nch[rel]) ? partials[rel * 64 + tid] : 0;
    sh[tid] = v; __syncthreads();
    for (int off = 1; off < 64; off <<= 1) {
        int t = (tid >= off) ? sh[tid - off] : 0; __syncthreads();
        sh[tid] += t; __syncthreads();
    }
    if (tid < nch[rel]) partials[rel * 64 + tid] = sh[tid] - v;
}
__global__ void __launch_bounds__(1024) scan_add_all(IPtr4 rp, const int* __restrict__ partials) {
    int rel, c; rel_chunk(blockIdx.x, rel, c);
    int n = nrel_of(rel);
    int tid = threadIdx.x;
    int i = c * 1024 + tid;
    if (i < n) rp.p[rel][i] += partials[rel * 64 + c];
    if (c == 0 && tid == 0) rp.p[rel][n] = En;
}
// scatter + per-edge weight (1/deg of dst) in CSR order
__global__ void scatter_all(CPtr4 src, CPtr4 dst, CPtr4 rp, int* fill_all, IPtr4 cs, FPtr4 we) {
    int i = blockIdx.x * 256 + threadIdx.x;
    if (i >= 4 * En) return;
    int rel = i / En; int e = i - rel * En;
    int d = dst.p[rel][e];
    int rb = rp.p[rel][d];
    int deg = rp.p[rel][d + 1] - rb;
    int pos = rb + atomicAdd(&fill_all[degoff_of(rel) + d], 1);
    cs.p[rel][pos] = src.p[rel][e];
    we.p[rel][pos] = 1.0f / (float)imax(deg, 1);
}

// ---------------- raw-feature segment mean (layer 0), 2-way edge ILP -------------------
struct RawDesc {
    const unsigned short* feat;   // stride 96
    const int* rowptr;
    const int* colsrc;
    unsigned short* out;          // stride 96
    int sh;                       // log2(col-groups of 4)
    int n_dst;
    int ocol;
};
__global__ void raw_agg(RawDesc d0, RawDesc d1, RawDesc d2, RawDesc d3) {
    RawDesc d = (blockIdx.y == 0) ? d0 : (blockIdx.y == 1) ? d1 : (blockIdx.y == 2) ? d2 : d3;
    int idx = blockIdx.x * 256 + threadIdx.x;
    int node = idx >> d.sh;
    int c4 = idx & ((1 << d.sh) - 1);
    if (node >= d.n_dst) return;
    int s = d.rowptr[node], e = d.rowptr[node + 1];
    float a0 = 0.f, a1 = 0.f, a2 = 0.f, a3 = 0.f;
    float b0 = 0.f, b1 = 0.f, b2 = 0.f, b3 = 0.f;
    int i = s;
    for (; i + 1 < e; i += 2) {
        int sc1 = d.colsrc[i], sc2 = d.colsrc[i + 1];
        ushort4 v1 = *reinterpret_cast<const ushort4*>(d.feat + (size_t)sc1 * KA + c4 * 4);
        ushort4 v2 = *reinterpret_cast<const ushort4*>(d.feat + (size_t)sc2 * KA + c4 * 4);
        a0 += bf2f(v1.x); a1 += bf2f(v1.y); a2 += bf2f(v1.z); a3 += bf2f(v1.w);
        b0 += bf2f(v2.x); b1 += bf2f(v2.y); b2 += bf2f(v2.z); b3 += bf2f(v2.w);
    }
    if (i < e) {
        int sc1 = d.colsrc[i];
        ushort4 v1 = *reinterpret_cast<const ushort4*>(d.feat + (size_t)sc1 * KA + c4 * 4);
        a0 += bf2f(v1.x); a1 += bf2f(v1.y); a2 += bf2f(v1.z); a3 += bf2f(v1.w);
    }
    a0 += b0; a1 += b1; a2 += b2; a3 += b3;
    float inv = 1.0f / (float)imax(e - s, 1);
    ushort4 o;
    o.x = f2bf(a0 * inv); o.y = f2bf(a1 * inv); o.z = f2bf(a2 * inv); o.w = f2bf(a3 * inv);
    *reinterpret_cast<ushort4*>(d.out + (size_t)node * KA + d.ocol + c4 * 4) = o;
}

// ---------------- layer-0 weight folding ------------------------------------------------
__global__ void wfold(const float* __restrict__ Wm, const float* __restrict__ Wr,
                      const float* __restrict__ Wpc, const float* __restrict__ Wp1,
                      const float* __restrict__ Wp2, unsigned short* __restrict__ Wt3) {
    __shared__ float cA[256], cB[256], cC[256];
    int n = blockIdx.x, mat = blockIdx.y, tid = threadIdx.x;
    for (int j = tid; j < 256; j += 128) {
        if (mat == 0) {
            cA[j] = 0.5f * (Wr[1 * 65536 + j * 256 + n] + Wr[3 * 65536 + j * 256 + n]);
            cB[j] = 0.5f * Wm[1 * 65536 + j * 256 + n];
            cC[j] = 0.5f * Wm[3 * 65536 + j * 256 + n];
        } else if (mat == 1) {
            cA[j] = Wm[0 * 65536 + j * 256 + n];
            cB[j] = Wr[0 * 65536 + j * 256 + n];
            cC[j] = 0.f;
        } else {
            cA[j] = Wm[2 * 65536 + j * 256 + n];
            cB[j] = Wr[2 * 65536 + j * 256 + n];
            cC[j] = 0.f;
        }
    }
    __syncthreads();
    int k = tid;
    if (k >= KA) return;
    float w = 0.f;
    if (k < 64) {
        for (int j = 0; j < 256; ++j) w = fmaf(Wpc[k * 256 + j], cA[j], w);
    } else if (k < 80) {
        const float* Wp = (mat == 2) ? Wp2 : Wp1;
        for (int j = 0; j < 256; ++j) w = fmaf(Wp[(k - 64) * 256 + j], cB[j], w);
    } else if (mat == 0) {
        for (int j = 0; j < 256; ++j) w = fmaf(Wp2[(k - 80) * 256 + j], cC[j], w);
    }
    Wt3[(size_t)mat * 256 * KA + n * KA + k] = f2bf(w);
}

__global__ void bias_fold(const float* __restrict__ Wm, const float* __restrict__ Wr,
                          const float* __restrict__ bm, const float* __restrict__ bpc,
                          const float* __restrict__ bp1, const float* __restrict__ bp2,
                          float* __restrict__ bC, float* __restrict__ bB1, float* __restrict__ bB2) {
    int n = blockIdx.x * 128 + threadIdx.x;
    if (n >= 256) return;
    float s0 = 0, s1 = 0, s2 = 0, t0 = 0, t1 = 0, u0 = 0, u1 = 0;
    for (int j = 0; j < 256; ++j) {
        float wr1 = Wr[1 * 65536 + j * 256 + n], wr3 = Wr[3 * 65536 + j * 256 + n];
        float wm1 = Wm[1 * 65536 + j * 256 + n], wm3 = Wm[3 * 65536 + j * 256 + n];
        float wm0 = Wm[0 * 65536 + j * 256 + n], wr0 = Wr[0 * 65536 + j * 256 + n];
        float wm2 = Wm[2 * 65536 + j * 256 + n], wr2 = Wr[2 * 65536 + j * 256 + n];
        float bc = bpc[j], b1 = bp1[j], b2 = bp2[j];
        s0 = fmaf(bc, 0.5f * (wr1 + wr3), s0);
        s1 = fmaf(b1, 0.5f * wm1, s1);
        s2 = fmaf(b2, 0.5f * wm3, s2);
        t0 = fmaf(bc, wm0, t0); t1 = fmaf(b1, wr0, t1);
        u0 = fmaf(bc, wm2, u0); u1 = fmaf(b2, wr2, u1);
    }
    bC[n]  = s0 + s1 + s2 + 0.5f * (bm[1 * 256 + n] + bm[3 * 256 + n]);
    bB1[n] = t0 + t1 + bm[0 * 256 + n];
    bB2[n] = u0 + u1 + bm[2 * 256 + n];
}

// layer-1 stacked per-graph weight [256][1792] transposed bf16 (x 1/3), + bias
__global__ void wpg_prep(const float* __restrict__ Wm, const float* __restrict__ Wr,
                         const float* __restrict__ bm, unsigned short* __restrict__ WPGt,
                         float* __restrict__ bPG) {
    int idx = blockIdx.x * 256 + threadIdx.x;
    const float third = 1.0f / 3.0f;
    if (idx < 256 * PGW) {
        int n = idx / PGW, k = idx - n * PGW;
        int blk = k >> 8, kk = k & 255;
        float v;
        switch (blk) {
            case 0:  v = 0.5f * Wm[1 * 65536 + kk * 256 + n]; break;
            case 1:  v = 0.5f * Wm[3 * 65536 + kk * 256 + n]; break;
            case 2:  v = 0.5f * (Wr[1 * 65536 + kk * 256 + n] + Wr[3 * 65536 + kk * 256 + n]); break;
            case 3:  v = Wm[0 * 65536 + kk * 256 + n]; break;
            case 4:  v = Wr[0 * 65536 + kk * 256 + n]; break;
            case 5:  v = Wm[2 * 65536 + kk * 256 + n]; break;
            default: v = Wr[2 * 65536 + kk * 256 + n]; break;
        }
        WPGt[idx] = f2bf(v * third);
    } else if (idx < 256 * PGW + 256) {
        int n = idx - 256 * PGW;
        bPG[n] = third * (0.5f * (bm[1 * 256 + n] + bm[3 * 256 + n]) + bm[0 * 256 + n] + bm[2 * 256 + n]);
    }
}

// ---------------- layer-0 GEMM: K=96, N=256, bias+relu, 3 fused instances --------------
struct G96 {
    const unsigned short* A;
    const unsigned short* Wt;
    const float* bias;
    unsigned short* C;
    int M;
};
__global__ void __launch_bounds__(256) gemm96(G96 g0, G96 g1, G96 g2) {
    G96 g = (blockIdx.y == 0) ? g0 : (blockIdx.y == 1) ? g1 : g2;
    const int m0 = blockIdx.x * 32;
    if (m0 >= g.M) return;
    const int tid = threadIdx.x;
    const int wid = tid >> 6, lane = tid & 63;
    const int llo = lane & 15, lhi = lane >> 4;
    const int cb = wid * 64;

    const unsigned short* pA[2];
#pragma unroll
    for (int rt = 0; rt < 2; ++rt)
        pA[rt] = g.A + (size_t)(m0 + rt * 16 + llo) * KA + lhi * 8;
    const unsigned short* pB[4];
#pragma unroll
    for (int ct = 0; ct < 4; ++ct)
        pB[ct] = g.Wt + (size_t)(cb + ct * 16 + llo) * KA + lhi * 8;

    f32x4 acc[2][4] = {};
    bf16x8 a0[2], a1[2], a2[2], b0[4], b1[4], b2[4];
#pragma unroll
    for (int t = 0; t < 2; ++t) {
        a0[t] = *reinterpret_cast<const bf16x8*>(pA[t]);
        a1[t] = *reinterpret_cast<const bf16x8*>(pA[t] + 32);
        a2[t] = *reinterpret_cast<const bf16x8*>(pA[t] + 64);
    }
#pragma unroll
    for (int t = 0; t < 4; ++t) {
        b0[t] = *reinterpret_cast<const bf16x8*>(pB[t]);
        b1[t] = *reinterpret_cast<const bf16x8*>(pB[t] + 32);
        b2[t] = *reinterpret_cast<const bf16x8*>(pB[t] + 64);
    }
#pragma unroll
    for (int rt = 0; rt < 2; ++rt)
#pragma unroll
        for (int ct = 0; ct < 4; ++ct) {
            acc[rt][ct] = __builtin_amdgcn_mfma_f32_16x16x32_bf16(b0[ct], a0[rt], acc[rt][ct], 0, 0, 0);
            acc[rt][ct] = __builtin_amdgcn_mfma_f32_16x16x32_bf16(b1[ct], a1[rt], acc[rt][ct], 0, 0, 0);
            acc[rt][ct] = __builtin_amdgcn_mfma_f32_16x16x32_bf16(b2[ct], a2[rt], acc[rt][ct], 0, 0, 0);
        }

#pragma unroll
    for (int rt = 0; rt < 2; ++rt) {
        const int row = m0 + rt * 16 + llo;
#pragma unroll
        for (int ct = 0; ct < 4; ++ct) {
            const int col0 = cb + ct * 16 + lhi * 4;
            float4 bv = *reinterpret_cast<const float4*>(g.bias + col0);
            float v0 = fmaxf(acc[rt][ct][0] + bv.x, 0.f);
            float v1 = fmaxf(acc[rt][ct][1] + bv.y, 0.f);
            float v2 = fmaxf(acc[rt][ct][2] + bv.z, 0.f);
            float v3 = fmaxf(acc[rt][ct][3] + bv.w, 0.f);
            ushort4 o;
            o.x = f2bf(v0); o.y = f2bf(v1); o.z = f2bf(v2); o.w = f2bf(v3);
            *reinterpret_cast<ushort4*>(g.C + (size_t)row * Hh + col0) = o;
        }
    }
}

// ---------------- per-graph aggregation: 7 descs x 2 range-halves, 4-way edge ILP ------
struct PDesc {
    const unsigned short* feat;   // [*][256]
    const int* bound;             // 513 entries (per dst node type)
    const int* rowptr;            // nullptr => plain mean over nodes
    const int* colsrc;
    const float* wedge;           // per-edge 1/deg in CSR order
};
struct PAll { PDesc d[7]; };
// part[(desc*2+z)*512*256 + g*256 + col] (f32)
__global__ void __launch_bounds__(256) pg_all(PAll all, float* __restrict__ part) {
    PDesc d = all.d[blockIdx.y];
    const int g = blockIdx.x, z = blockIdx.z;
    const int tid = threadIdx.x, wid = tid >> 6, lane = tid & 63;
    const int ns = d.bound[g], ne = d.bound[g + 1];
    float r0 = 0.f, r1 = 0.f, r2 = 0.f, r3 = 0.f;
    if (d.rowptr) {
        const int es = d.rowptr[ns], ee = d.rowptr[ne];
        const int mid = (es + ee) >> 1;
        const int s = z ? mid : es, e = z ? ee : mid;
        float a[4][4] = {};
        for (int i = s + wid * 4; i < e; i += 16) {
#pragma unroll
            for (int j = 0; j < 4; ++j) {
                int ij = i + j;
                bool ok = ij < e;
                int idx = ok ? ij : (e - 1);
                int sc = d.colsrc[idx];
                float w = ok ? d.wedge[idx] : 0.f;
                ushort4 v = *reinterpret_cast<const ushort4*>(d.feat + (size_t)sc * Hh + lane * 4);
                a[j][0] = fmaf(bf2f(v.x), w, a[j][0]);
                a[j][1] = fmaf(bf2f(v.y), w, a[j][1]);
                a[j][2] = fmaf(bf2f(v.z), w, a[j][2]);
                a[j][3] = fmaf(bf2f(v.w), w, a[j][3]);
            }
        }
        r0 = (a[0][0] + a[1][0]) + (a[2][0] + a[3][0]);
        r1 = (a[0][1] + a[1][1]) + (a[2][1] + a[3][1]);
        r2 = (a[0][2] + a[1][2]) + (a[2][2] + a[3][2]);
        r3 = (a[0][3] + a[1][3]) + (a[2][3] + a[3][3]);
    } else {
        const int mid = (ns + ne) >> 1;
        const int s = z ? mid : ns, e = z ? ne : mid;
        float c0 = 0.f, c1 = 0.f, c2 = 0.f, c3 = 0.f;
        for (int n = s + wid * 2; n < e; n += 8) {
            ushort4 v1 = *reinterpret_cast<const ushort4*>(d.feat + (size_t)n * Hh + lane * 4);
            int n2 = n + 1;
            if (n2 < e) {
                ushort4 v2 = *reinterpret_cast<const ushort4*>(d.feat + (size_t)n2 * Hh + lane * 4);
                c0 += bf2f(v2.x); c1 += bf2f(v2.y); c2 += bf2f(v2.z); c3 += bf2f(v2.w);
            }
            r0 += bf2f(v1.x); r1 += bf2f(v1.y); r2 += bf2f(v1.z); r3 += bf2f(v1.w);
        }
        r0 += c0; r1 += c1; r2 += c2; r3 += c3;
    }
    __shared__ float sh[4][256];
    sh[wid][lane * 4 + 0] = r0; sh[wid][lane * 4 + 1] = r1;
    sh[wid][lane * 4 + 2] = r2; sh[wid][lane * 4 + 3] = r3;
    __syncthreads();
    float r = (sh[0][tid] + sh[1][tid]) + (sh[2][tid] + sh[3][tid]);
    part[(size_t)((blockIdx.y * 2 + z) * Bn + g) * 256 + tid] = r;
}

// combine 2 halves, normalize by per-graph node count, write bf16 PG
__global__ void __launch_bounds__(256) pg_combine(const float* __restrict__ part,
                                                  const int* __restrict__ bounds,
                                                  unsigned short* __restrict__ PG) {
    const int otab[7] = { 0, 256, 512, 768, 1024, 1280, 1536 };
    const int btab[7] = { 0, 0, 0, 1, 1, 2, 2 };
    int g = blockIdx.x, dsc = blockIdx.y, tid = threadIdx.x;
    const int* b = bounds + btab[dsc] * (Bn + 1);
    int cnt = b[g + 1] - b[g];
    float s = part[(size_t)((dsc * 2 + 0) * Bn + g) * 256 + tid] +
              part[(size_t)((dsc * 2 + 1) * Bn + g) * 256 + tid];
    s *= 1.0f / (float)imax(cnt, 1);
    PG[(size_t)g * PGW + otab[dsc] + tid] = f2bf(s);
}

// ---------------- final: emb = PG @ WPGt + bPG (MFMA); out = emb @ Wg + bg -------------
__global__ void graph_bounds_all(const int* __restrict__ bc, const int* __restrict__ b1,
                                 const int* __restrict__ b2, int* __restrict__ bound) {
    int idx = blockIdx.x * 256 + threadIdx.x;
    if (idx >= 3 * (Bn + 1)) return;
    int t = idx / (Bn + 1); int b = idx - t * (Bn + 1);
    const int* batch = (t == 0) ? bc : (t == 1) ? b1 : b2;
    int n = (t == 0) ? NCn : (t == 1) ? N1n : N2n;
    int lo = 0, hi = n;
    while (lo < hi) { int mid = (lo + hi) >> 1; if (batch[mid] < b) lo = mid + 1; else hi = mid; }
    bound[idx] = lo;
}

__global__ void __launch_bounds__(256) gemm_emb(const unsigned short* __restrict__ PG,
                                                const unsigned short* __restrict__ WPGt,
                                                const float* __restrict__ bPG,
                                                float* __restrict__ emb) {
    constexpr int KSTEPS = PGW / 32;
    const int m0 = blockIdx.x * 32;
    const int tid = threadIdx.x;
    const int wid = tid >> 6, lane = tid & 63;
    const int llo = lane & 15, lhi = lane >> 4;
    const int cb = wid * 64;

    const unsigned short* pA[2];
#pragma unroll
    for (int rt = 0; rt < 2; ++rt)
        pA[rt] = PG + (size_t)(m0 + rt * 16 + llo) * PGW + lhi * 8;
    const unsigned short* pB[4];
#pragma unroll
    for (int ct = 0; ct < 4; ++ct)
        pB[ct] = WPGt + (size_t)(cb + ct * 16 + llo) * PGW + lhi * 8;

    f32x4 acc[2][4] = {};
    bf16x8 aX[2], bX[4], aY[2], bY[4];
    auto LD = [&](bf16x8 (&a)[2], bf16x8 (&b)[4], int ks) {
        if (ks < KSTEPS) {
            const int ko = ks * 32;
#pragma unroll
            for (int t = 0; t < 2; ++t) a[t] = *reinterpret_cast<const bf16x8*>(pA[t] + ko);
#pragma unroll
            for (int t = 0; t < 4; ++t) b[t] = *reinterpret_cast<const bf16x8*>(pB[t] + ko);
        }
    };
    auto FM = [&](bf16x8 (&a)[2], bf16x8 (&b)[4]) {
#pragma unroll
        for (int rt = 0; rt < 2; ++rt)
#pragma unroll
            for (int ct = 0; ct < 4; ++ct)
                acc[rt][ct] = __builtin_amdgcn_mfma_f32_16x16x32_bf16(b[ct], a[rt], acc[rt][ct], 0, 0, 0);
    };
    LD(aX, bX, 0);
    for (int ks = 0; ks < KSTEPS; ks += 2) {
        LD(aY, bY, ks + 1);
        FM(aX, bX);
        LD(aX, bX, ks + 2);
        FM(aY, bY);
    }

#pragma unroll
    for (int rt = 0; rt < 2; ++rt) {
        const int row = m0 + rt * 16 + llo;
#pragma unroll
        for (int ct = 0; ct < 4; ++ct) {
            const int col0 = cb + ct * 16 + lhi * 4;
            float4 bv = *reinterpret_cast<const float4*>(bPG + col0);
            float4 o;
            o.x = acc[rt][ct][0] + bv.x; o.y = acc[rt][ct][1] + bv.y;
            o.z = acc[rt][ct][2] + bv.z; o.w = acc[rt][ct][3] + bv.w;
            *reinterpret_cast<float4*>(emb + (size_t)row * Hh + col0) = o;
        }
    }
}

__global__ void __launch_bounds__(128) out_final(const float* __restrict__ emb,
                                                 const float* __restrict__ Wg,
                                                 const float* __restrict__ bg,
                                                 float* __restrict__ out) {
    __shared__ float es_[256];
    int g = blockIdx.x, o = threadIdx.x;
    es_[o] = emb[(size_t)g * Hh + o];
    es_[o + 128] = emb[(size_t)g * Hh + 128 + o];
    __syncthreads();
    float acc = bg[o];
#pragma unroll 8
    for (int k = 0; k < 256; ++k) acc = fmaf(es_[k], Wg[k * OUTn + o], acc);
    out[(size_t)g * OUTn + o] = acc;
}

// ---------------- host orchestration ----------------------------------------------------
extern "C" void kernel_launch(void* const* d_in, const int* in_sizes, int n_in,
                              void* d_out, int out_size, void* d_ws, size_t ws_size,
                              hipStream_t stream) {
    const float* x_central = (const float*)d_in[0];
    const float* x_cont    = (const float*)d_in[1];
    const float* x_categ   = (const float*)d_in[2];
    const int* ei_c2cont   = (const int*)d_in[3];
    const int* ei_cont2c   = (const int*)d_in[4];
    const int* ei_c2categ  = (const int*)d_in[5];
    const int* ei_categ2c  = (const int*)d_in[6];
    const int* batch_central = (const int*)d_in[7];
    const int* batch_cont    = (const int*)d_in[8];
    const int* batch_categ   = (const int*)d_in[9];
    const float* Wp_central = (const float*)d_in[11];
    const float* bp_central = (const float*)d_in[12];
    const float* Wp_cont    = (const float*)d_in[13];
    const float* bp_cont    = (const float*)d_in[14];
    const float* Wp_categ   = (const float*)d_in[15];
    const float* bp_categ   = (const float*)d_in[16];
    const float* W_msg  = (const float*)d_in[17];
    const float* b_msg  = (const float*)d_in[18];
    const float* W_root = (const float*)d_in[19];
    const float* Wg     = (const float*)d_in[20];
    const float* bg     = (const float*)d_in[21];
    float* out = (float*)d_out;

    char* base = (char*)d_ws;
    size_t off = 0;
    auto alloc = [&](size_t bytes) -> void* {
        off = (off + 255) & ~(size_t)255;
        void* p = base + off; off += bytes; return p;
    };

    unsigned short* A0  = (unsigned short*)alloc((size_t)NCn * KA * 2);
    unsigned short* A1  = (unsigned short*)alloc((size_t)N1n * KA * 2);
    unsigned short* A2  = (unsigned short*)alloc((size_t)N2n * KA * 2);
    unsigned short* hc1 = (unsigned short*)alloc((size_t)NCn * Hh * 2);
    unsigned short* h11 = (unsigned short*)alloc((size_t)N1n * Hh * 2);
    unsigned short* h21 = (unsigned short*)alloc((size_t)N2n * Hh * 2);
    unsigned short* PG  = (unsigned short*)alloc((size_t)Bn * PGW * 2);
    float* emb          = (float*)alloc((size_t)Bn * Hh * 4);
    float* part         = (float*)alloc((size_t)14 * Bn * 256 * 4);   // 7 descs x 2 halves

    unsigned short* Wt3  = (unsigned short*)alloc((size_t)3 * 256 * KA * 2);
    unsigned short* WPGt = (unsigned short*)alloc((size_t)256 * PGW * 2);
    float* bC  = (float*)alloc(256 * 4);
    float* bB1 = (float*)alloc(256 * 4);
    float* bB2 = (float*)alloc(256 * 4);
    float* bPG = (float*)alloc(256 * 4);

    const int ndst[4] = { N1n, NCn, N2n, NCn };
    int* rp[4]; int* cs[4]; float* we[4];
    for (int r = 0; r < 4; ++r) {
        rp[r] = (int*)alloc((size_t)(ndst[r] + 1) * 4);
        cs[r] = (int*)alloc((size_t)En * 4);
        we[r] = (float*)alloc((size_t)En * 4);
    }
    int* deg_fill = (int*)alloc((size_t)320000 * 4);   // [0,160000) deg, [160000,320000) fill
    int* partials = (int*)alloc(256 * 4);
    int* bounds   = (int*)alloc((size_t)3 * (Bn + 1) * 4);
    (void)ws_size; (void)in_sizes; (void)n_in; (void)out_size;

    const float* Wm0 = W_msg;
    const float* Wr0 = W_root;
    const float* Wm1 = W_msg  + (size_t)4 * 65536;
    const float* Wr1 = W_root + (size_t)4 * 65536;
    const float* bm0 = b_msg;
    const float* bm1 = b_msg + 4 * 256;

    // --- packing + weight prep ---
    pack_inputs<<<5000, 256, 0, stream>>>(x_central, x_cont, x_categ, A0, A1, A2);
    wfold<<<dim3(256, 3), 128, 0, stream>>>(Wm0, Wr0, Wp_central, Wp_cont, Wp_categ, Wt3);
    bias_fold<<<2, 128, 0, stream>>>(Wm0, Wr0, bm0, bp_central, bp_cont, bp_categ, bC, bB1, bB2);
    wpg_prep<<<1793, 256, 0, stream>>>(Wm1, Wr1, bm1, WPGt, bPG);
    graph_bounds_all<<<7, 256, 0, stream>>>(batch_central, batch_cont, batch_categ, bounds);

    // --- CSR build (dst side) ---
    CPtr4 srcs = {{ ei_c2cont, ei_cont2c, ei_c2categ, ei_categ2c }};
    CPtr4 dsts = {{ ei_c2cont + En, ei_cont2c + En, ei_c2categ + En, ei_categ2c + En }};
    IPtr4 rps  = {{ rp[0], rp[1], rp[2], rp[3] }};
    CPtr4 rpc  = {{ rp[0], rp[1], rp[2], rp[3] }};
    IPtr4 css  = {{ cs[0], cs[1], cs[2], cs[3] }};
    FPtr4 wes  = {{ we[0], we[1], we[2], we[3] }};
    zero_i32<<<1250, 256, 0, stream>>>(deg_fill, 320000);
    deg_count_all<<<3125, 256, 0, stream>>>(dsts, deg_fill);
    scan_chunk_all<<<158, 1024, 0, stream>>>(deg_fill, rps, partials);
    scan_partials_all<<<4, 64, 0, stream>>>(partials);
    scan_add_all<<<158, 1024, 0, stream>>>(rps, partials);
    scatter_all<<<3125, 256, 0, stream>>>(srcs, dsts, rpc, deg_fill + 160000, css, wes);

    // --- layer-0 raw aggregations (into A panels) ---
    RawDesc r0 = { A1 + 64, rp[1], cs[1], A0, 2, NCn, 64 };
    RawDesc r1 = { A2 + 64, rp[3], cs[3], A0, 2, NCn, 80 };
    RawDesc r2 = { A0,      rp[0], cs[0], A1, 4, N1n, 0 };
    RawDesc r3 = { A0,      rp[2], cs[2], A2, 4, N2n, 0 };
    raw_agg<<<dim3(3750, 4), 256, 0, stream>>>(r0, r1, r2, r3);

    // --- layer-0 GEMMs (K=96, bias+relu) ---
    G96 gc = { A0, Wt3,                 bC,  hc1, NCn };
    G96 g1 = { A1, Wt3 + 1 * 256 * KA,  bB1, h11, N1n };
    G96 g2 = { A2, Wt3 + 2 * 256 * KA,  bB2, h21, N2n };
    gemm96<<<dim3(1875, 3), 256, 0, stream>>>(g1, g2, gc);

    // --- layer-1 collapsed: per-graph aggregation (7 descs x 2 halves) ---
    PAll pa;
    pa.d[0] = { h11, bounds,                rp[1], cs[1], we[1] };   // -> ocol 0
    pa.d[1] = { h21, bounds,                rp[3], cs[3], we[3] };   // -> ocol 256
    pa.d[2] = { hc1, bounds,                nullptr, nullptr, nullptr }; // -> 512
    pa.d[3] = { hc1, bounds + (Bn + 1),     rp[0], cs[0], we[0] };   // -> 768
    pa.d[4] = { h11, bounds + (Bn + 1),     nullptr, nullptr, nullptr }; // -> 1024
    pa.d[5] = { hc1, bounds + 2 * (Bn + 1), rp[2], cs[2], we[2] };   // -> 1280
    pa.d[6] = { h21, bounds + 2 * (Bn + 1), nullptr, nullptr, nullptr }; // -> 1536
    pg_all<<<dim3(Bn, 7, 2), 256, 0, stream>>>(pa, part);
    pg_combine<<<dim3(Bn, 7), 256, 0, stream>>>(part, bounds, PG);

    // --- final ---
    gemm_emb<<<Bn / 32, 256, 0, stream>>>(PG, WPGt, bPG, emb);
    out_final<<<Bn, 128, 0, stream>>>(emb, Wg, bg, out);
}

// Round 8
// 338.011 us; speedup vs baseline: 4.9287x; 1.0408x over previous
//
#include <hip/hip_runtime.h>

#define Hh   256
#define NCn  20000
#define N1n  60000
#define N2n  60000
#define En   200000
#define Bn   512
#define OUTn 128
#define KA   96        // layer-0 packed-A stride / GEMM K
#define PGW  1792      // per-graph concat width (7 x 256)

using bf16x8 = __attribute__((ext_vector_type(8))) __bf16;
using f32x4  = __attribute__((ext_vector_type(4))) float;
using f32x2  = __attribute__((ext_vector_type(2))) float;

__device__ __forceinline__ float bf2f(unsigned short u) {
    union { unsigned int i; float f; } v; v.i = ((unsigned int)u) << 16; return v.f;
}
__device__ __forceinline__ unsigned short f2bf(float f) {
    union { float f; unsigned int i; } v; v.f = f;
    unsigned int r = v.i + 0x7FFFu + ((v.i >> 16) & 1u);
    return (unsigned short)(r >> 16);
}
__device__ __forceinline__ int imax(int a, int b) { return a > b ? a : b; }

// ---- fp8 e4m3 pack/unpack (hardware cvt on gfx950; guarded manual fallback) -----------
#if __has_builtin(__builtin_amdgcn_cvt_pk_fp8_f32) && __has_builtin(__builtin_amdgcn_cvt_pk_f32_fp8)
__device__ __forceinline__ unsigned int pack4_fp8(float v0, float v1, float v2, float v3) {
    int r = __builtin_amdgcn_cvt_pk_fp8_f32(v0, v1, 0, false);
    r = __builtin_amdgcn_cvt_pk_fp8_f32(v2, v3, r, true);
    return (unsigned int)r;
}
__device__ __forceinline__ void unpack4_fp8(unsigned int u, float& v0, float& v1, float& v2, float& v3) {
    f32x2 lo = __builtin_amdgcn_cvt_pk_f32_fp8((int)u, false);
    f32x2 hi = __builtin_amdgcn_cvt_pk_f32_fp8((int)u, true);
    v0 = lo[0]; v1 = lo[1]; v2 = hi[0]; v3 = hi[1];
}
#else
__device__ __forceinline__ unsigned char f32_to_fp8_1(float f) {
    union { float f; unsigned int i; } v; v.f = f;
    unsigned int s = (v.i >> 24) & 0x80u;
    float af = fabsf(f);
    if (!(af > 0.f)) return (unsigned char)s;
    if (af > 448.f) af = 448.f;
    v.f = af;
    int e = (int)((v.i >> 23) & 0xff) - 127;
    unsigned int m = v.i & 0x7fffffu;
    if (e < -9) return (unsigned char)s;
    if (e < -6) {
        int rb = 21 + (-6 - e) - 1;
        unsigned int man = 0x800000u | m;
        unsigned int keep = man >> (rb + 1);
        unsigned int rem = man & ((1u << (rb + 1)) - 1);
        unsigned int half = 1u << rb;
        keep += (rem > half) || (rem == half && (keep & 1));
        return (unsigned char)(s | keep);
    }
    unsigned int keep = m >> 20;
    unsigned int rem = m & 0xfffffu;
    keep += (rem > 0x80000u) || (rem == 0x80000u && (keep & 1));
    unsigned int ee = (unsigned int)(e + 7);
    if (keep == 8) { keep = 0; ee += 1; }
    if (ee >= 16) { ee = 15; keep = 6; }
    return (unsigned char)(s | (ee << 3) | keep);
}
__device__ __forceinline__ unsigned int pack4_fp8(float v0, float v1, float v2, float v3) {
    return (unsigned int)f32_to_fp8_1(v0) | ((unsigned int)f32_to_fp8_1(v1) << 8) |
           ((unsigned int)f32_to_fp8_1(v2) << 16) | ((unsigned int)f32_to_fp8_1(v3) << 24);
}
__device__ __forceinline__ float fp8_to_f32_1(unsigned int b) {
    unsigned int s = b >> 7, e = (b >> 3) & 15u, m = b & 7u;
    float v;
    if (e == 0) v = (float)m * (1.0f / 512.0f);
    else { union { unsigned int i; float f; } u; u.i = ((e + 120u) << 23) | (m << 20); v = u.f; }
    return s ? -v : v;
}
__device__ __forceinline__ void unpack4_fp8(unsigned int u, float& v0, float& v1, float& v2, float& v3) {
    v0 = fp8_to_f32_1(u & 0xffu); v1 = fp8_to_f32_1((u >> 8) & 0xffu);
    v2 = fp8_to_f32_1((u >> 16) & 0xffu); v3 = fp8_to_f32_1((u >> 24) & 0xffu);
}
#endif

struct CPtr4 { const int* p[4]; };
struct IPtr4 { int* p[4]; };
struct FPtr4 { float* p[4]; };

// ---------------- input packing: raw features -> bf16 A-panels (float4 vectorized) -----
__global__ void pack_inputs(const float* __restrict__ xc, const float* __restrict__ x1,
                            const float* __restrict__ x2, unsigned short* __restrict__ A0,
                            unsigned short* __restrict__ A1, unsigned short* __restrict__ A2) {
    int idx = blockIdx.x * 256 + threadIdx.x;   // one ushort4 (4 cols) per thread
    const int c0 = NCn * 16, c1 = c0 + N1n * 8, c2 = c1 + N2n * 8;
    if (idx < c0) {
        int m = idx >> 4, c = (idx & 15) * 4;
        float4 v = *reinterpret_cast<const float4*>(xc + (size_t)m * 64 + c);
        ushort4 o = { f2bf(v.x), f2bf(v.y), f2bf(v.z), f2bf(v.w) };
        *reinterpret_cast<ushort4*>(A0 + (size_t)m * KA + c) = o;
    } else if (idx < c2) {
        bool is1 = idx < c1;
        int i = idx - (is1 ? c0 : c1);
        int m = i >> 3, c = (i & 7) * 4;
        const float* x = is1 ? x1 : x2;
        unsigned short* A = is1 ? A1 : A2;
        ushort4 o = { 0, 0, 0, 0 };
        if (c < 16) {
            float4 v = *reinterpret_cast<const float4*>(x + (size_t)m * 16 + c);
            o.x = f2bf(v.x); o.y = f2bf(v.y); o.z = f2bf(v.z); o.w = f2bf(v.w);
        }
        *reinterpret_cast<ushort4*>(A + (size_t)m * KA + 64 + c) = o;
    }
}

// ---------------- CSR build (relation-batched, dst side only) --------------------------
__device__ __forceinline__ int degoff_of(int rel) {
    const int t[4] = { 0, N1n, N1n + NCn, N1n + NCn + N2n };
    return t[rel];
}
__device__ __forceinline__ int nrel_of(int rel) {
    const int t[4] = { N1n, NCn, N2n, NCn };
    return t[rel];
}
__device__ __forceinline__ void rel_chunk(int b, int& rel, int& c) {
    if (b < 59)       { rel = 0; c = b; }
    else if (b < 79)  { rel = 1; c = b - 59; }
    else if (b < 138) { rel = 2; c = b - 79; }
    else              { rel = 3; c = b - 138; }
}
__global__ void zero_i32(int* p, int n) {
    int i = blockIdx.x * 256 + threadIdx.x; if (i < n) p[i] = 0;
}
__global__ void deg_count_all(CPtr4 dst, int* __restrict__ deg_all) {
    int i = blockIdx.x * 256 + threadIdx.x;
    if (i >= 4 * En) return;
    int rel = i / En; int e = i - rel * En;
    atomicAdd(&deg_all[degoff_of(rel) + dst.p[rel][e]], 1);
}
__global__ void __launch_bounds__(1024) scan_chunk_all(const int* __restrict__ deg_all,
                                                       IPtr4 rp, int* __restrict__ partials) {
    int rel, c; rel_chunk(blockIdx.x, rel, c);
    int n = nrel_of(rel);
    __shared__ int sh[1024];
    int tid = threadIdx.x;
    int i = c * 1024 + tid;
    int v = (i < n) ? deg_all[degoff_of(rel) + i] : 0;
    sh[tid] = v; __syncthreads();
    for (int off = 1; off < 1024; off <<= 1) {
        int t = (tid >= off) ? sh[tid - off] : 0; __syncthreads();
        sh[tid] += t; __syncthreads();
    }
    if (i < n) rp.p[rel][i] = sh[tid] - v;
    if (tid == 1023) partials[rel * 64 + c] = sh[1023];
}
__global__ void scan_partials_all(int* partials) {
    const int nch[4] = { 59, 20, 59, 20 };
    int rel = blockIdx.x;
    __shared__ int sh[64];
    int tid = threadIdx.x;
    int v = (tid < nch[rel]) ? partials[rel * 64 + tid] : 0;
    sh[tid] = v; __syncthreads();
    for (int off = 1; off < 64; off <<= 1) {
        int t = (tid >= off) ? sh[tid - off] : 0; __syncthreads();
        sh[tid] += t; __syncthreads();
    }
    if (tid < nch[rel]) partials[rel * 64 + tid] = sh[tid] - v;
}
__global__ void __launch_bounds__(1024) scan_add_all(IPtr4 rp, const int* __restrict__ partials) {
    int rel, c; rel_chunk(blockIdx.x, rel, c);
    int n = nrel_of(rel);
    int tid = threadIdx.x;
    int i = c * 1024 + tid;
    if (i < n) rp.p[rel][i] += partials[rel * 64 + c];
    if (c == 0 && tid == 0) rp.p[rel][n] = En;
}
// scatter + per-edge weight (1/deg of dst) in CSR order
__global__ void scatter_all(CPtr4 src, CPtr4 dst, CPtr4 rp, int* fill_all, IPtr4 cs, FPtr4 we) {
    int i = blockIdx.x * 256 + threadIdx.x;
    if (i >= 4 * En) return;
    int rel = i / En; int e = i - rel * En;
    int d = dst.p[rel][e];
    int rb = rp.p[rel][d];
    int deg = rp.p[rel][d + 1] - rb;
    int pos = rb + atomicAdd(&fill_all[degoff_of(rel) + d], 1);
    cs.p[rel][pos] = src.p[rel][e];
    we.p[rel][pos] = 1.0f / (float)imax(deg, 1);
}

// ---------------- raw-feature segment mean (layer 0), 2-way edge ILP -------------------
struct RawDesc {
    const unsigned short* feat;   // stride 96
    const int* rowptr;
    const int* colsrc;
    unsigned short* out;          // stride 96
    int sh;                       // log2(col-groups of 4)
    int n_dst;
    int ocol;
};
__global__ void raw_agg(RawDesc d0, RawDesc d1, RawDesc d2, RawDesc d3) {
    RawDesc d = (blockIdx.y == 0) ? d0 : (blockIdx.y == 1) ? d1 : (blockIdx.y == 2) ? d2 : d3;
    int idx = blockIdx.x * 256 + threadIdx.x;
    int node = idx >> d.sh;
    int c4 = idx & ((1 << d.sh) - 1);
    if (node >= d.n_dst) return;
    int s = d.rowptr[node], e = d.rowptr[node + 1];
    float a0 = 0.f, a1 = 0.f, a2 = 0.f, a3 = 0.f;
    float b0 = 0.f, b1 = 0.f, b2 = 0.f, b3 = 0.f;
    int i = s;
    for (; i + 1 < e; i += 2) {
        int sc1 = d.colsrc[i], sc2 = d.colsrc[i + 1];
        ushort4 v1 = *reinterpret_cast<const ushort4*>(d.feat + (size_t)sc1 * KA + c4 * 4);
        ushort4 v2 = *reinterpret_cast<const ushort4*>(d.feat + (size_t)sc2 * KA + c4 * 4);
        a0 += bf2f(v1.x); a1 += bf2f(v1.y); a2 += bf2f(v1.z); a3 += bf2f(v1.w);
        b0 += bf2f(v2.x); b1 += bf2f(v2.y); b2 += bf2f(v2.z); b3 += bf2f(v2.w);
    }
    if (i < e) {
        int sc1 = d.colsrc[i];
        ushort4 v1 = *reinterpret_cast<const ushort4*>(d.feat + (size_t)sc1 * KA + c4 * 4);
        a0 += bf2f(v1.x); a1 += bf2f(v1.y); a2 += bf2f(v1.z); a3 += bf2f(v1.w);
    }
    a0 += b0; a1 += b1; a2 += b2; a3 += b3;
    float inv = 1.0f / (float)imax(e - s, 1);
    ushort4 o;
    o.x = f2bf(a0 * inv); o.y = f2bf(a1 * inv); o.z = f2bf(a2 * inv); o.w = f2bf(a3 * inv);
    *reinterpret_cast<ushort4*>(d.out + (size_t)node * KA + d.ocol + c4 * 4) = o;
}

// ---------------- layer-0 weight folding ------------------------------------------------
__global__ void wfold(const float* __restrict__ Wm, const float* __restrict__ Wr,
                      const float* __restrict__ Wpc, const float* __restrict__ Wp1,
                      const float* __restrict__ Wp2, unsigned short* __restrict__ Wt3) {
    __shared__ float cA[256], cB[256], cC[256];
    int n = blockIdx.x, mat = blockIdx.y, tid = threadIdx.x;
    for (int j = tid; j < 256; j += 128) {
        if (mat == 0) {
            cA[j] = 0.5f * (Wr[1 * 65536 + j * 256 + n] + Wr[3 * 65536 + j * 256 + n]);
            cB[j] = 0.5f * Wm[1 * 65536 + j * 256 + n];
            cC[j] = 0.5f * Wm[3 * 65536 + j * 256 + n];
        } else if (mat == 1) {
            cA[j] = Wm[0 * 65536 + j * 256 + n];
            cB[j] = Wr[0 * 65536 + j * 256 + n];
            cC[j] = 0.f;
        } else {
            cA[j] = Wm[2 * 65536 + j * 256 + n];
            cB[j] = Wr[2 * 65536 + j * 256 + n];
            cC[j] = 0.f;
        }
    }
    __syncthreads();
    int k = tid;
    if (k >= KA) return;
    float w = 0.f;
    if (k < 64) {
        for (int j = 0; j < 256; ++j) w = fmaf(Wpc[k * 256 + j], cA[j], w);
    } else if (k < 80) {
        const float* Wp = (mat == 2) ? Wp2 : Wp1;
        for (int j = 0; j < 256; ++j) w = fmaf(Wp[(k - 64) * 256 + j], cB[j], w);
    } else if (mat == 0) {
        for (int j = 0; j < 256; ++j) w = fmaf(Wp2[(k - 80) * 256 + j], cC[j], w);
    }
    Wt3[(size_t)mat * 256 * KA + n * KA + k] = f2bf(w);
}

__global__ void bias_fold(const float* __restrict__ Wm, const float* __restrict__ Wr,
                          const float* __restrict__ bm, const float* __restrict__ bpc,
                          const float* __restrict__ bp1, const float* __restrict__ bp2,
                          float* __restrict__ bC, float* __restrict__ bB1, float* __restrict__ bB2) {
    int n = blockIdx.x * 128 + threadIdx.x;
    if (n >= 256) return;
    float s0 = 0, s1 = 0, s2 = 0, t0 = 0, t1 = 0, u0 = 0, u1 = 0;
    for (int j = 0; j < 256; ++j) {
        float wr1 = Wr[1 * 65536 + j * 256 + n], wr3 = Wr[3 * 65536 + j * 256 + n];
        float wm1 = Wm[1 * 65536 + j * 256 + n], wm3 = Wm[3 * 65536 + j * 256 + n];
        float wm0 = Wm[0 * 65536 + j * 256 + n], wr0 = Wr[0 * 65536 + j * 256 + n];
        float wm2 = Wm[2 * 65536 + j * 256 + n], wr2 = Wr[2 * 65536 + j * 256 + n];
        float bc = bpc[j], b1 = bp1[j], b2 = bp2[j];
        s0 = fmaf(bc, 0.5f * (wr1 + wr3), s0);
        s1 = fmaf(b1, 0.5f * wm1, s1);
        s2 = fmaf(b2, 0.5f * wm3, s2);
        t0 = fmaf(bc, wm0, t0); t1 = fmaf(b1, wr0, t1);
        u0 = fmaf(bc, wm2, u0); u1 = fmaf(b2, wr2, u1);
    }
    bC[n]  = s0 + s1 + s2 + 0.5f * (bm[1 * 256 + n] + bm[3 * 256 + n]);
    bB1[n] = t0 + t1 + bm[0 * 256 + n];
    bB2[n] = u0 + u1 + bm[2 * 256 + n];
}

// layer-1 stacked per-graph weight [256][1792] transposed bf16 (x 1/3), + bias
__global__ void wpg_prep(const float* __restrict__ Wm, const float* __restrict__ Wr,
                         const float* __restrict__ bm, unsigned short* __restrict__ WPGt,
                         float* __restrict__ bPG) {
    int idx = blockIdx.x * 256 + threadIdx.x;
    const float third = 1.0f / 3.0f;
    if (idx < 256 * PGW) {
        int n = idx / PGW, k = idx - n * PGW;
        int blk = k >> 8, kk = k & 255;
        float v;
        switch (blk) {
            case 0:  v = 0.5f * Wm[1 * 65536 + kk * 256 + n]; break;
            case 1:  v = 0.5f * Wm[3 * 65536 + kk * 256 + n]; break;
            case 2:  v = 0.5f * (Wr[1 * 65536 + kk * 256 + n] + Wr[3 * 65536 + kk * 256 + n]); break;
            case 3:  v = Wm[0 * 65536 + kk * 256 + n]; break;
            case 4:  v = Wr[0 * 65536 + kk * 256 + n]; break;
            case 5:  v = Wm[2 * 65536 + kk * 256 + n]; break;
            default: v = Wr[2 * 65536 + kk * 256 + n]; break;
        }
        WPGt[idx] = f2bf(v * third);
    } else if (idx < 256 * PGW + 256) {
        int n = idx - 256 * PGW;
        bPG[n] = third * (0.5f * (bm[1 * 256 + n] + bm[3 * 256 + n]) + bm[0 * 256 + n] + bm[2 * 256 + n]);
    }
}

// ---------------- layer-0 GEMM: K=96, N=256, bias+relu, fp8 output ---------------------
struct G96 {
    const unsigned short* A;
    const unsigned short* Wt;
    const float* bias;
    unsigned char* C;          // fp8 e4m3, stride 256 B
    int M;
};
__global__ void __launch_bounds__(256) gemm96(G96 g0, G96 g1, G96 g2) {
    G96 g = (blockIdx.y == 0) ? g0 : (blockIdx.y == 1) ? g1 : g2;
    const int m0 = blockIdx.x * 32;
    if (m0 >= g.M) return;
    const int tid = threadIdx.x;
    const int wid = tid >> 6, lane = tid & 63;
    const int llo = lane & 15, lhi = lane >> 4;
    const int cb = wid * 64;

    const unsigned short* pA[2];
#pragma unroll
    for (int rt = 0; rt < 2; ++rt)
        pA[rt] = g.A + (size_t)(m0 + rt * 16 + llo) * KA + lhi * 8;
    const unsigned short* pB[4];
#pragma unroll
    for (int ct = 0; ct < 4; ++ct)
        pB[ct] = g.Wt + (size_t)(cb + ct * 16 + llo) * KA + lhi * 8;

    f32x4 acc[2][4] = {};
    bf16x8 a0[2], a1[2], a2[2], b0[4], b1[4], b2[4];
#pragma unroll
    for (int t = 0; t < 2; ++t) {
        a0[t] = *reinterpret_cast<const bf16x8*>(pA[t]);
        a1[t] = *reinterpret_cast<const bf16x8*>(pA[t] + 32);
        a2[t] = *reinterpret_cast<const bf16x8*>(pA[t] + 64);
    }
#pragma unroll
    for (int t = 0; t < 4; ++t) {
        b0[t] = *reinterpret_cast<const bf16x8*>(pB[t]);
        b1[t] = *reinterpret_cast<const bf16x8*>(pB[t] + 32);
        b2[t] = *reinterpret_cast<const bf16x8*>(pB[t] + 64);
    }
#pragma unroll
    for (int rt = 0; rt < 2; ++rt)
#pragma unroll
        for (int ct = 0; ct < 4; ++ct) {
            acc[rt][ct] = __builtin_amdgcn_mfma_f32_16x16x32_bf16(b0[ct], a0[rt], acc[rt][ct], 0, 0, 0);
            acc[rt][ct] = __builtin_amdgcn_mfma_f32_16x16x32_bf16(b1[ct], a1[rt], acc[rt][ct], 0, 0, 0);
            acc[rt][ct] = __builtin_amdgcn_mfma_f32_16x16x32_bf16(b2[ct], a2[rt], acc[rt][ct], 0, 0, 0);
        }

#pragma unroll
    for (int rt = 0; rt < 2; ++rt) {
        const int row = m0 + rt * 16 + llo;
#pragma unroll
        for (int ct = 0; ct < 4; ++ct) {
            const int col0 = cb + ct * 16 + lhi * 4;
            float4 bv = *reinterpret_cast<const float4*>(g.bias + col0);
            float v0 = fmaxf(acc[rt][ct][0] + bv.x, 0.f);
            float v1 = fmaxf(acc[rt][ct][1] + bv.y, 0.f);
            float v2 = fmaxf(acc[rt][ct][2] + bv.z, 0.f);
            float v3 = fmaxf(acc[rt][ct][3] + bv.w, 0.f);
            unsigned int o = pack4_fp8(v0, v1, v2, v3);
            *reinterpret_cast<unsigned int*>(g.C + (size_t)row * 256 + col0) = o;
        }
    }
}

// ---------------- per-graph aggregation: 7 descs x 2 range-halves, 4-way edge ILP ------
// feat tables are fp8 e4m3, stride 256 B; lane reads 4 cols (uint).
struct PDesc {
    const unsigned char* feat;    // [*][256] fp8
    const int* bound;             // 513 entries (per dst node type)
    const int* rowptr;            // nullptr => plain mean over nodes
    const int* colsrc;
    const float* wedge;           // per-edge 1/deg in CSR order
};
struct PAll { PDesc d[7]; };
// part[(desc*2+z)*512*256 + g*256 + col] (f32)
__global__ void __launch_bounds__(256) pg_all(PAll all, float* __restrict__ part) {
    PDesc d = all.d[blockIdx.y];
    const int g = blockIdx.x, z = blockIdx.z;
    const int tid = threadIdx.x, wid = tid >> 6, lane = tid & 63;
    const int ns = d.bound[g], ne = d.bound[g + 1];
    float r0 = 0.f, r1 = 0.f, r2 = 0.f, r3 = 0.f;
    if (d.rowptr) {
        const int es = d.rowptr[ns], ee = d.rowptr[ne];
        const int mid = (es + ee) >> 1;
        const int s = z ? mid : es, e = z ? ee : mid;
        float a[4][4] = {};
        for (int i = s + wid * 4; i < e; i += 16) {
#pragma unroll
            for (int j = 0; j < 4; ++j) {
                int ij = i + j;
                bool ok = ij < e;
                int idx = ok ? ij : (e - 1);
                int sc = d.colsrc[idx];
                float w = ok ? d.wedge[idx] : 0.f;
                unsigned int u = *reinterpret_cast<const unsigned int*>(
                    d.feat + (size_t)sc * 256 + lane * 4);
                float f0, f1, f2, f3;
                unpack4_fp8(u, f0, f1, f2, f3);
                a[j][0] = fmaf(f0, w, a[j][0]);
                a[j][1] = fmaf(f1, w, a[j][1]);
                a[j][2] = fmaf(f2, w, a[j][2]);
                a[j][3] = fmaf(f3, w, a[j][3]);
            }
        }
        r0 = (a[0][0] + a[1][0]) + (a[2][0] + a[3][0]);
        r1 = (a[0][1] + a[1][1]) + (a[2][1] + a[3][1]);
        r2 = (a[0][2] + a[1][2]) + (a[2][2] + a[3][2]);
        r3 = (a[0][3] + a[1][3]) + (a[2][3] + a[3][3]);
    } else {
        const int mid = (ns + ne) >> 1;
        const int s = z ? mid : ns, e = z ? ne : mid;
        float c0 = 0.f, c1 = 0.f, c2 = 0.f, c3 = 0.f;
        for (int n = s + wid * 2; n < e; n += 8) {
            unsigned int u1 = *reinterpret_cast<const unsigned int*>(
                d.feat + (size_t)n * 256 + lane * 4);
            int n2 = n + 1;
            if (n2 < e) {
                unsigned int u2 = *reinterpret_cast<const unsigned int*>(
                    d.feat + (size_t)n2 * 256 + lane * 4);
                float f0, f1, f2, f3;
                unpack4_fp8(u2, f0, f1, f2, f3);
                c0 += f0; c1 += f1; c2 += f2; c3 += f3;
            }
            float f0, f1, f2, f3;
            unpack4_fp8(u1, f0, f1, f2, f3);
            r0 += f0; r1 += f1; r2 += f2; r3 += f3;
        }
        r0 += c0; r1 += c1; r2 += c2; r3 += c3;
    }
    __shared__ float sh[4][256];
    sh[wid][lane * 4 + 0] = r0; sh[wid][lane * 4 + 1] = r1;
    sh[wid][lane * 4 + 2] = r2; sh[wid][lane * 4 + 3] = r3;
    __syncthreads();
    float r = (sh[0][tid] + sh[1][tid]) + (sh[2][tid] + sh[3][tid]);
    part[(size_t)((blockIdx.y * 2 + z) * Bn + g) * 256 + tid] = r;
}

// combine 2 halves, normalize by per-graph node count, write bf16 PG
__global__ void __launch_bounds__(256) pg_combine(const float* __restrict__ part,
                                                  const int* __restrict__ bounds,
                                                  unsigned short* __restrict__ PG) {
    const int otab[7] = { 0, 256, 512, 768, 1024, 1280, 1536 };
    const int btab[7] = { 0, 0, 0, 1, 1, 2, 2 };
    int g = blockIdx.x, dsc = blockIdx.y, tid = threadIdx.x;
    const int* b = bounds + btab[dsc] * (Bn + 1);
    int cnt = b[g + 1] - b[g];
    float s = part[(size_t)((dsc * 2 + 0) * Bn + g) * 256 + tid] +
              part[(size_t)((dsc * 2 + 1) * Bn + g) * 256 + tid];
    s *= 1.0f / (float)imax(cnt, 1);
    PG[(size_t)g * PGW + otab[dsc] + tid] = f2bf(s);
}

// ---------------- final: emb = PG @ WPGt + bPG (MFMA); out = emb @ Wg + bg -------------
__global__ void graph_bounds_all(const int* __restrict__ bc, const int* __restrict__ b1,
                                 const int* __restrict__ b2, int* __restrict__ bound) {
    int idx = blockIdx.x * 256 + threadIdx.x;
    if (idx >= 3 * (Bn + 1)) return;
    int t = idx / (Bn + 1); int b = idx - t * (Bn + 1);
    const int* batch = (t == 0) ? bc : (t == 1) ? b1 : b2;
    int n = (t == 0) ? NCn : (t == 1) ? N1n : N2n;
    int lo = 0, hi = n;
    while (lo < hi) { int mid = (lo + hi) >> 1; if (batch[mid] < b) lo = mid + 1; else hi = mid; }
    bound[idx] = lo;
}

__global__ void __launch_bounds__(256) gemm_emb(const unsigned short* __restrict__ PG,
                                                const unsigned short* __restrict__ WPGt,
                                                const float* __restrict__ bPG,
                                                float* __restrict__ emb) {
    constexpr int KSTEPS = PGW / 32;
    const int m0 = blockIdx.x * 32;
    const int tid = threadIdx.x;
    const int wid = tid >> 6, lane = tid & 63;
    const int llo = lane & 15, lhi = lane >> 4;
    const int cb = wid * 64;

    const unsigned short* pA[2];
#pragma unroll
    for (int rt = 0; rt < 2; ++rt)
        pA[rt] = PG + (size_t)(m0 + rt * 16 + llo) * PGW + lhi * 8;
    const unsigned short* pB[4];
#pragma unroll
    for (int ct = 0; ct < 4; ++ct)
        pB[ct] = WPGt + (size_t)(cb + ct * 16 + llo) * PGW + lhi * 8;

    f32x4 acc[2][4] = {};
    bf16x8 aX[2], bX[4], aY[2], bY[4];
    auto LD = [&](bf16x8 (&a)[2], bf16x8 (&b)[4], int ks) {
        if (ks < KSTEPS) {
            const int ko = ks * 32;
#pragma unroll
            for (int t = 0; t < 2; ++t) a[t] = *reinterpret_cast<const bf16x8*>(pA[t] + ko);
#pragma unroll
            for (int t = 0; t < 4; ++t) b[t] = *reinterpret_cast<const bf16x8*>(pB[t] + ko);
        }
    };
    auto FM = [&](bf16x8 (&a)[2], bf16x8 (&b)[4]) {
#pragma unroll
        for (int rt = 0; rt < 2; ++rt)
#pragma unroll
            for (int ct = 0; ct < 4; ++ct)
                acc[rt][ct] = __builtin_amdgcn_mfma_f32_16x16x32_bf16(b[ct], a[rt], acc[rt][ct], 0, 0, 0);
    };
    LD(aX, bX, 0);
    for (int ks = 0; ks < KSTEPS; ks += 2) {
        LD(aY, bY, ks + 1);
        FM(aX, bX);
        LD(aX, bX, ks + 2);
        FM(aY, bY);
    }

#pragma unroll
    for (int rt = 0; rt < 2; ++rt) {
        const int row = m0 + rt * 16 + llo;
#pragma unroll
        for (int ct = 0; ct < 4; ++ct) {
            const int col0 = cb + ct * 16 + lhi * 4;
            float4 bv = *reinterpret_cast<const float4*>(bPG + col0);
            float4 o;
            o.x = acc[rt][ct][0] + bv.x; o.y = acc[rt][ct][1] + bv.y;
            o.z = acc[rt][ct][2] + bv.z; o.w = acc[rt][ct][3] + bv.w;
            *reinterpret_cast<float4*>(emb + (size_t)row * Hh + col0) = o;
        }
    }
}

__global__ void __launch_bounds__(128) out_final(const float* __restrict__ emb,
                                                 const float* __restrict__ Wg,
                                                 const float* __restrict__ bg,
                                                 float* __restrict__ out) {
    __shared__ float es_[256];
    int g = blockIdx.x, o = threadIdx.x;
    es_[o] = emb[(size_t)g * Hh + o];
    es_[o + 128] = emb[(size_t)g * Hh + 128 + o];
    __syncthreads();
    float acc = bg[o];
#pragma unroll 8
    for (int k = 0; k < 256; ++k) acc = fmaf(es_[k], Wg[k * OUTn + o], acc);
    out[(size_t)g * OUTn + o] = acc;
}

// ---------------- host orchestration ----------------------------------------------------
extern "C" void kernel_launch(void* const* d_in, const int* in_sizes, int n_in,
                              void* d_out, int out_size, void* d_ws, size_t ws_size,
                              hipStream_t stream) {
    const float* x_central = (const float*)d_in[0];
    const float* x_cont    = (const float*)d_in[1];
    const float* x_categ   = (const float*)d_in[2];
    const int* ei_c2cont   = (const int*)d_in[3];
    const int* ei_cont2c   = (const int*)d_in[4];
    const int* ei_c2categ  = (const int*)d_in[5];
    const int* ei_categ2c  = (const int*)d_in[6];
    const int* batch_central = (const int*)d_in[7];
    const int* batch_cont    = (const int*)d_in[8];
    const int* batch_categ   = (const int*)d_in[9];
    const float* Wp_central = (const float*)d_in[11];
    const float* bp_central = (const float*)d_in[12];
    const float* Wp_cont    = (const float*)d_in[13];
    const float* bp_cont    = (const float*)d_in[14];
    const float* Wp_categ   = (const float*)d_in[15];
    const float* bp_categ   = (const float*)d_in[16];
    const float* W_msg  = (const float*)d_in[17];
    const float* b_msg  = (const float*)d_in[18];
    const float* W_root = (const float*)d_in[19];
    const float* Wg     = (const float*)d_in[20];
    const float* bg     = (const float*)d_in[21];
    float* out = (float*)d_out;

    char* base = (char*)d_ws;
    size_t off = 0;
    auto alloc = [&](size_t bytes) -> void* {
        off = (off + 255) & ~(size_t)255;
        void* p = base + off; off += bytes; return p;
    };

    unsigned short* A0  = (unsigned short*)alloc((size_t)NCn * KA * 2);
    unsigned short* A1  = (unsigned short*)alloc((size_t)N1n * KA * 2);
    unsigned short* A2  = (unsigned short*)alloc((size_t)N2n * KA * 2);
    unsigned char* hc1  = (unsigned char*)alloc((size_t)NCn * 256);
    unsigned char* h11  = (unsigned char*)alloc((size_t)N1n * 256);
    unsigned char* h21  = (unsigned char*)alloc((size_t)N2n * 256);
    unsigned short* PG  = (unsigned short*)alloc((size_t)Bn * PGW * 2);
    float* emb          = (float*)alloc((size_t)Bn * Hh * 4);
    float* part         = (float*)alloc((size_t)14 * Bn * 256 * 4);   // 7 descs x 2 halves

    unsigned short* Wt3  = (unsigned short*)alloc((size_t)3 * 256 * KA * 2);
    unsigned short* WPGt = (unsigned short*)alloc((size_t)256 * PGW * 2);
    float* bC  = (float*)alloc(256 * 4);
    float* bB1 = (float*)alloc(256 * 4);
    float* bB2 = (float*)alloc(256 * 4);
    float* bPG = (float*)alloc(256 * 4);

    const int ndst[4] = { N1n, NCn, N2n, NCn };
    int* rp[4]; int* cs[4]; float* we[4];
    for (int r = 0; r < 4; ++r) {
        rp[r] = (int*)alloc((size_t)(ndst[r] + 1) * 4);
        cs[r] = (int*)alloc((size_t)En * 4);
        we[r] = (float*)alloc((size_t)En * 4);
    }
    int* deg_fill = (int*)alloc((size_t)320000 * 4);   // [0,160000) deg, [160000,320000) fill
    int* partials = (int*)alloc(256 * 4);
    int* bounds   = (int*)alloc((size_t)3 * (Bn + 1) * 4);
    (void)ws_size; (void)in_sizes; (void)n_in; (void)out_size;

    const float* Wm0 = W_msg;
    const float* Wr0 = W_root;
    const float* Wm1 = W_msg  + (size_t)4 * 65536;
    const float* Wr1 = W_root + (size_t)4 * 65536;
    const float* bm0 = b_msg;
    const float* bm1 = b_msg + 4 * 256;

    // --- packing + weight prep ---
    pack_inputs<<<5000, 256, 0, stream>>>(x_central, x_cont, x_categ, A0, A1, A2);
    wfold<<<dim3(256, 3), 128, 0, stream>>>(Wm0, Wr0, Wp_central, Wp_cont, Wp_categ, Wt3);
    bias_fold<<<2, 128, 0, stream>>>(Wm0, Wr0, bm0, bp_central, bp_cont, bp_categ, bC, bB1, bB2);
    wpg_prep<<<1793, 256, 0, stream>>>(Wm1, Wr1, bm1, WPGt, bPG);
    graph_bounds_all<<<7, 256, 0, stream>>>(batch_central, batch_cont, batch_categ, bounds);

    // --- CSR build (dst side) ---
    CPtr4 srcs = {{ ei_c2cont, ei_cont2c, ei_c2categ, ei_categ2c }};
    CPtr4 dsts = {{ ei_c2cont + En, ei_cont2c + En, ei_c2categ + En, ei_categ2c + En }};
    IPtr4 rps  = {{ rp[0], rp[1], rp[2], rp[3] }};
    CPtr4 rpc  = {{ rp[0], rp[1], rp[2], rp[3] }};
    IPtr4 css  = {{ cs[0], cs[1], cs[2], cs[3] }};
    FPtr4 wes  = {{ we[0], we[1], we[2], we[3] }};
    zero_i32<<<1250, 256, 0, stream>>>(deg_fill, 320000);
    deg_count_all<<<3125, 256, 0, stream>>>(dsts, deg_fill);
    scan_chunk_all<<<158, 1024, 0, stream>>>(deg_fill, rps, partials);
    scan_partials_all<<<4, 64, 0, stream>>>(partials);
    scan_add_all<<<158, 1024, 0, stream>>>(rps, partials);
    scatter_all<<<3125, 256, 0, stream>>>(srcs, dsts, rpc, deg_fill + 160000, css, wes);

    // --- layer-0 raw aggregations (into A panels) ---
    RawDesc r0 = { A1 + 64, rp[1], cs[1], A0, 2, NCn, 64 };
    RawDesc r1 = { A2 + 64, rp[3], cs[3], A0, 2, NCn, 80 };
    RawDesc r2 = { A0,      rp[0], cs[0], A1, 4, N1n, 0 };
    RawDesc r3 = { A0,      rp[2], cs[2], A2, 4, N2n, 0 };
    raw_agg<<<dim3(3750, 4), 256, 0, stream>>>(r0, r1, r2, r3);

    // --- layer-0 GEMMs (K=96, bias+relu, fp8 out) ---
    G96 gc = { A0, Wt3,                 bC,  hc1, NCn };
    G96 g1 = { A1, Wt3 + 1 * 256 * KA,  bB1, h11, N1n };
    G96 g2 = { A2, Wt3 + 2 * 256 * KA,  bB2, h21, N2n };
    gemm96<<<dim3(1875, 3), 256, 0, stream>>>(g1, g2, gc);

    // --- layer-1 collapsed: per-graph aggregation (7 descs x 2 halves, fp8 gathers) ---
    PAll pa;
    pa.d[0] = { h11, bounds,                rp[1], cs[1], we[1] };   // -> ocol 0
    pa.d[1] = { h21, bounds,                rp[3], cs[3], we[3] };   // -> ocol 256
    pa.d[2] = { hc1, bounds,                nullptr, nullptr, nullptr }; // -> 512
    pa.d[3] = { hc1, bounds + (Bn + 1),     rp[0], cs[0], we[0] };   // -> 768
    pa.d[4] = { h11, bounds + (Bn + 1),     nullptr, nullptr, nullptr }; // -> 1024
    pa.d[5] = { hc1, bounds + 2 * (Bn + 1), rp[2], cs[2], we[2] };   // -> 1280
    pa.d[6] = { h21, bounds + 2 * (Bn + 1), nullptr, nullptr, nullptr }; // -> 1536
    pg_all<<<dim3(Bn, 7, 2), 256, 0, stream>>>(pa, part);
    pg_combine<<<dim3(Bn, 7), 256, 0, stream>>>(part, bounds, PG);

    // --- final ---
    gemm_emb<<<Bn / 32, 256, 0, stream>>>(PG, WPGt, bPG, emb);
    out_final<<<Bn, 128, 0, stream>>>(emb, Wg, bg, out);
}